// Round 10
// baseline (615.075 us; speedup 1.0000x reference)
//
#include <hip/hip_runtime.h>
#include <cfloat>
#include <cstdint>

// ---------------- problem constants ----------------
#define NC 1536   // 3*H concatenated projection width

// d_out float offsets: emb[16,1024] | out[16] | smiles_attn_pool[16,2048] | seqs_attn_pool[16,128]
#define OUT_EMB 0
#define OUT_OUT 16384
#define OUT_A1  16400
#define OUT_A2  49168

// ws byte offsets
#define WS_NRM_S   0u
#define WS_NRM_M   32768u
#define WS_BCAT    360448u
#define WS_LOG1    366592u
#define WS_PP1     505856u
#define WS_POOL2   768000u
#define WS_EMB     800768u
#define WS_H1      866304u
#define WS_H2      931840u
#define WS_WCT     1048576u
#define WS_SMISNB  2621440u
#define WS_PSMIS   4718592u
#define WS_SEQSOUT 11010048u
#define WS_SEQSNB  15204352u
#define WS_PSEQS   48758784u
#define WS_SMILOUT WS_SEQSNB          // seqs_nb dead after GEMM1; reuse for smiles_out
#define WS_S2      149422080u          // ws total need ~216.5 MB
// norm partials are consumed before Pseqs is written -> alias that region
#define WS_PART    WS_PSEQS
#define WS_PARTM   (WS_PSEQS + 2097152u)

typedef float f32x4 __attribute__((ext_vector_type(4)));
typedef __bf16 bf16x8 __attribute__((ext_vector_type(8)));
typedef unsigned short u16x8 __attribute__((ext_vector_type(8)));

__device__ __forceinline__ float bf2f(unsigned short h) {
  return __uint_as_float(((unsigned int)h) << 16);
}
__device__ __forceinline__ unsigned short f2bf(float f) {
  unsigned int u = __float_as_uint(f);
  return (unsigned short)((u + 0x7FFFu + ((u >> 16) & 1u)) >> 16);
}
__device__ __forceinline__ void gld16(const unsigned short* g, unsigned short* l) {
  __builtin_amdgcn_global_load_lds(
      (__attribute__((address_space(1))) unsigned int*)(uintptr_t)g,
      (__attribute__((address_space(3))) unsigned int*)l, 16, 0, 0);
}

// position-space mask -> element-space mask for the anti-diagonal transpose layout:
// element 2c sits at position 15-c (low half), element 2c+1 at position 31-c (high half)
__device__ __forceinline__ unsigned pos2elem(unsigned m) {
  unsigned lo = __brev(m & 0xFFFFu) >> 16;   // bit i = m bit (15-i)
  unsigned hi = __brev(m >> 16) >> 16;       // bit i = m bit (31-i)
  lo = (lo | (lo << 8)) & 0x00FF00FFu;
  lo = (lo | (lo << 4)) & 0x0F0F0F0Fu;
  lo = (lo | (lo << 2)) & 0x33333333u;
  lo = (lo | (lo << 1)) & 0x55555555u;
  hi = (hi | (hi << 8)) & 0x00FF00FFu;
  hi = (hi | (hi << 4)) & 0x0F0F0F0Fu;
  hi = (hi | (hi << 2)) & 0x33333333u;
  hi = (hi | (hi << 1)) & 0x55555555u;
  return lo | (hi << 1);
}

#define TRANSPOSE16(B)                                                                             \
  {                                                                                                \
    unsigned t;                                                                                    \
    t = (B[0] ^ (B[8] >> 8)) & 0x00FF00FFu; B[0] ^= t; B[8] ^= (t << 8);                           \
    t = (B[1] ^ (B[9] >> 8)) & 0x00FF00FFu; B[1] ^= t; B[9] ^= (t << 8);                           \
    t = (B[2] ^ (B[10] >> 8)) & 0x00FF00FFu; B[2] ^= t; B[10] ^= (t << 8);                         \
    t = (B[3] ^ (B[11] >> 8)) & 0x00FF00FFu; B[3] ^= t; B[11] ^= (t << 8);                         \
    t = (B[4] ^ (B[12] >> 8)) & 0x00FF00FFu; B[4] ^= t; B[12] ^= (t << 8);                         \
    t = (B[5] ^ (B[13] >> 8)) & 0x00FF00FFu; B[5] ^= t; B[13] ^= (t << 8);                         \
    t = (B[6] ^ (B[14] >> 8)) & 0x00FF00FFu; B[6] ^= t; B[14] ^= (t << 8);                         \
    t = (B[7] ^ (B[15] >> 8)) & 0x00FF00FFu; B[7] ^= t; B[15] ^= (t << 8);                         \
    t = (B[0] ^ (B[4] >> 4)) & 0x0F0F0F0Fu; B[0] ^= t; B[4] ^= (t << 4);                           \
    t = (B[1] ^ (B[5] >> 4)) & 0x0F0F0F0Fu; B[1] ^= t; B[5] ^= (t << 4);                           \
    t = (B[2] ^ (B[6] >> 4)) & 0x0F0F0F0Fu; B[2] ^= t; B[6] ^= (t << 4);                           \
    t = (B[3] ^ (B[7] >> 4)) & 0x0F0F0F0Fu; B[3] ^= t; B[7] ^= (t << 4);                           \
    t = (B[8] ^ (B[12] >> 4)) & 0x0F0F0F0Fu; B[8] ^= t; B[12] ^= (t << 4);                         \
    t = (B[9] ^ (B[13] >> 4)) & 0x0F0F0F0Fu; B[9] ^= t; B[13] ^= (t << 4);                         \
    t = (B[10] ^ (B[14] >> 4)) & 0x0F0F0F0Fu; B[10] ^= t; B[14] ^= (t << 4);                       \
    t = (B[11] ^ (B[15] >> 4)) & 0x0F0F0F0Fu; B[11] ^= t; B[15] ^= (t << 4);                       \
    t = (B[0] ^ (B[2] >> 2)) & 0x33333333u; B[0] ^= t; B[2] ^= (t << 2);                           \
    t = (B[1] ^ (B[3] >> 2)) & 0x33333333u; B[1] ^= t; B[3] ^= (t << 2);                           \
    t = (B[4] ^ (B[6] >> 2)) & 0x33333333u; B[4] ^= t; B[6] ^= (t << 2);                           \
    t = (B[5] ^ (B[7] >> 2)) & 0x33333333u; B[5] ^= t; B[7] ^= (t << 2);                           \
    t = (B[8] ^ (B[10] >> 2)) & 0x33333333u; B[8] ^= t; B[10] ^= (t << 2);                         \
    t = (B[9] ^ (B[11] >> 2)) & 0x33333333u; B[9] ^= t; B[11] ^= (t << 2);                         \
    t = (B[12] ^ (B[14] >> 2)) & 0x33333333u; B[12] ^= t; B[14] ^= (t << 2);                       \
    t = (B[13] ^ (B[15] >> 2)) & 0x33333333u; B[13] ^= t; B[15] ^= (t << 2);                       \
    t = (B[0] ^ (B[1] >> 1)) & 0x55555555u; B[0] ^= t; B[1] ^= (t << 1);                           \
    t = (B[2] ^ (B[3] >> 1)) & 0x55555555u; B[2] ^= t; B[3] ^= (t << 1);                           \
    t = (B[4] ^ (B[5] >> 1)) & 0x55555555u; B[4] ^= t; B[5] ^= (t << 1);                           \
    t = (B[6] ^ (B[7] >> 1)) & 0x55555555u; B[6] ^= t; B[7] ^= (t << 1);                           \
    t = (B[8] ^ (B[9] >> 1)) & 0x55555555u; B[8] ^= t; B[9] ^= (t << 1);                           \
    t = (B[10] ^ (B[11] >> 1)) & 0x55555555u; B[10] ^= t; B[11] ^= (t << 1);                       \
    t = (B[12] ^ (B[13] >> 1)) & 0x55555555u; B[12] ^= t; B[13] ^= (t << 1);                       \
    t = (B[14] ^ (B[15] >> 1)) & 0x55555555u; B[14] ^= t; B[15] ^= (t << 1);                       \
  }

// ---------------- column-wise l2 norms (axis=1) ----------------
// thread t owns 4 consecutive cols (float4); block owns a row-slab -> full MLP, coalesced.
__global__ __launch_bounds__(128) void knorm_part(const float* __restrict__ x, float* __restrict__ part,
                                                  int SL, int NS) {
  int ls = blockIdx.x, b = blockIdx.y, t = threadIdx.x;
  const float* xp = x + ((size_t)b * NS + ls) * SL * 512 + t * 4;
  float ax = 0.f, ay = 0.f, az = 0.f, aw = 0.f;
  for (int l = 0; l < SL; ++l) {
    float4 v = *(const float4*)(xp + (size_t)l * 512);
    ax += v.x * v.x; ay += v.y * v.y; az += v.z * v.z; aw += v.w * v.w;
  }
  float4 r = {ax, ay, az, aw};
  *(float4*)(part + ((size_t)(b * NS + ls)) * 512 + t * 4) = r;
}

// grid 32 x 256: bh = b*2 + colhalf
__global__ __launch_bounds__(256) void knorm_fin(const float* __restrict__ part, float* __restrict__ inv, int NS) {
  int bh = blockIdx.x, t = threadIdx.x;
  int b = bh >> 1, col = (bh & 1) * 256 + t;
  float s = 0.f;
  for (int j = 0; j < NS; ++j) s += part[((size_t)(b * NS + j)) * 512 + col];
  inv[(size_t)b * 512 + col] = 1.f / fmaxf(sqrtf(s), 1e-12f);
}

__global__ __launch_bounds__(256) void kcast(const float* __restrict__ x, const float* __restrict__ inv,
                                             unsigned short* __restrict__ o, int shiftB, int total) {
  int i4 = (blockIdx.x * 256 + threadIdx.x) * 4;
  if (i4 >= total) return;
  int b = i4 >> shiftB;
  float4 v = *(const float4*)(x + i4);
  float4 nv = *(const float4*)(inv + (b << 9) + (i4 & 511));
  ushort4 r;
  r.x = f2bf(v.x * nv.x); r.y = f2bf(v.y * nv.y);
  r.z = f2bf(v.z * nv.z); r.w = f2bf(v.w * nv.w);
  *(ushort4*)(o + i4) = r;
}

// ---------------- weight prep: WcatT[1536][512] bf16 (B^T layout), bcat ----------------
__global__ __launch_bounds__(256) void kprepw(const float* __restrict__ Wq, const float* __restrict__ Wk,
                                              const float* __restrict__ Wv, unsigned short* __restrict__ WT) {
  __shared__ float T[32][33];
  int ti = blockIdx.x, tj = blockIdx.y, m = blockIdx.z;
  const float* W = m == 0 ? Wq : (m == 1 ? Wk : Wv);
  int c = threadIdx.x & 31, r0 = threadIdx.x >> 5;
#pragma unroll
  for (int j = 0; j < 4; ++j) {
    int r = r0 + j * 8;
    T[r][c] = W[(size_t)(ti * 32 + r) * 512 + tj * 32 + c];
  }
  __syncthreads();
#pragma unroll
  for (int j = 0; j < 4; ++j) {
    int r = r0 + j * 8;
    WT[(size_t)(m * 512 + tj * 32 + r) * 512 + ti * 32 + c] = f2bf(T[c][r]);
  }
}

__global__ void kprepb(const float* bq, const float* bk, const float* bv, float* bcat) {
  int i = blockIdx.x * 256 + threadIdx.x;
  if (i >= 1536) return;
  bcat[i] = i < 512 ? bq[i] : (i < 1024 ? bk[i - 512] : bv[i - 1024]);
}

// ---------------- bf16 MFMA GEMM: C[M,N] = A[M,K] @ Bt[N,K]^T + bias ----------------
// v4: A via LDS double-buffer (async DMA); B fragments loaded DIRECTLY from global
// (L2-resident, 1.5 MB) with one-iteration register prefetch -> barrier-independent,
// stays in flight across __syncthreads. Halves LDS pipe pressure. XCD remap kept.
__global__ __launch_bounds__(256) void kgemm(const unsigned short* __restrict__ A,
                                             const unsigned short* __restrict__ Bt,
                                             const float* __restrict__ bias,
                                             unsigned short* __restrict__ C,
                                             int K, int N, int NT) {
  __shared__ unsigned short As[2][128 * 32];
  int tid = threadIdx.x, lane = tid & 63, wave = tid >> 6;
  int id = blockIdx.x;
  int xcd = id & 7, j = id >> 3;
  int mloc = j / NT, n = j - mloc * NT;
  int m0 = (mloc * 8 + xcd) * 128, n0 = n * 128;
  f32x4 acc[4][4] = {};
  int wm = (wave >> 1) * 64, wn = (wave & 1) * 64;
  int frow = lane & 15, fk = (lane >> 4) * 8;

  auto stageA = [&](int buf, int k0) {
#pragma unroll
    for (int jj = 0; jj < 2; ++jj) {
      int ch = jj * 256 + tid;
      int row = ch >> 2, kc = (ch & 3) * 8;
      gld16(A + (size_t)(m0 + row) * K + k0 + kc, As[buf] + ch * 8);
    }
  };

  // per-lane global pointers for B fragments (row n0+wn+nt*16+frow, k offset fk)
  const unsigned short* bp0 = Bt + (size_t)(n0 + wn + 0 * 16 + frow) * K + fk;
  const unsigned short* bp1 = Bt + (size_t)(n0 + wn + 1 * 16 + frow) * K + fk;
  const unsigned short* bp2 = Bt + (size_t)(n0 + wn + 2 * 16 + frow) * K + fk;
  const unsigned short* bp3 = Bt + (size_t)(n0 + wn + 3 * 16 + frow) * K + fk;

  stageA(0, 0);
  bf16x8 bpref[4];
  bpref[0] = *(const bf16x8*)bp0;
  bpref[1] = *(const bf16x8*)bp1;
  bpref[2] = *(const bf16x8*)bp2;
  bpref[3] = *(const bf16x8*)bp3;
  __syncthreads();
  int nk = K >> 5;
  for (int it = 0; it < nk; ++it) {
    int cur = it & 1;
    if (it + 1 < nk) stageA(cur ^ 1, (it + 1) << 5);   // A prefetch; lands during MFMAs
    bf16x8 bcur[4];
#pragma unroll
    for (int nt = 0; nt < 4; ++nt) bcur[nt] = bpref[nt];
    if (it + 1 < nk) {                                  // B prefetch: barrier-independent
      int off = (it + 1) << 5;
      bpref[0] = *(const bf16x8*)(bp0 + off);
      bpref[1] = *(const bf16x8*)(bp1 + off);
      bpref[2] = *(const bf16x8*)(bp2 + off);
      bpref[3] = *(const bf16x8*)(bp3 + off);
    }
    bf16x8 af[4];
#pragma unroll
    for (int mt = 0; mt < 4; ++mt) af[mt] = *(const bf16x8*)&As[cur][(wm + mt * 16 + frow) * 32 + fk];
#pragma unroll
    for (int mt = 0; mt < 4; ++mt)
#pragma unroll
      for (int nt = 0; nt < 4; ++nt)
        acc[mt][nt] = __builtin_amdgcn_mfma_f32_16x16x32_bf16(af[mt], bcur[nt], acc[mt][nt], 0, 0, 0);
    __syncthreads();   // publishes A prefetch (drain overlapped by the 16 MFMAs above)
  }
  int q = lane >> 4, c15 = lane & 15;
#pragma unroll
  for (int mt = 0; mt < 4; ++mt)
#pragma unroll
    for (int nt = 0; nt < 4; ++nt) {
      int col = n0 + wn + nt * 16 + c15;
      float bv = bias ? bias[col] : 0.f;
#pragma unroll
      for (int r = 0; r < 4; ++r) {
        int row = m0 + wm + mt * 16 + q * 4 + r;
        C[(size_t)row * N + col] = f2bf(acc[mt][nt][r] + bv);
      }
    }
}

// ---------------- fusion 1: Q=seqs(2048) K,V=smis(128); top-32 of 128 ----------------
// v4: 4 waves/block; per-lane bit-plane radix (16 rows selected per wave in one pass),
// XOR-swizzled Vt, ones-column MFMA denominator.
__global__ __launch_bounds__(256) void kfusion1(const unsigned short* __restrict__ Pseqs,
                                                const unsigned short* __restrict__ Psmis,
                                                unsigned short* __restrict__ smil) {
  constexpr int PP = 136;                 // halfword pitch, rows 16B-aligned
  __shared__ unsigned short Sc[64 * PP];  // scores, then unnormalized P (bf16)
  __shared__ unsigned short Vt[64 * PP];  // V^T [e][s ^ (e&56)] (swizzled)
  int tid = threadIdx.x, lane = tid & 63, w = tid >> 6;
  int lt = blockIdx.x, h = blockIdx.y, b = blockIdx.z;
  int l0 = lt * 64;
  int frow = lane & 15, q = lane >> 4, fk8 = q * 8;

  // stage V^T, XOR swizzle on s-blocks
  for (int ch = tid; ch < 1024; ch += 256) {
    int s = ch >> 3, e8 = (ch & 7) * 8;
    u16x8 vv = *(const u16x8*)&Psmis[(size_t)(b * 128 + s) * NC + 1024 + h * 64 + e8];
#pragma unroll
    for (int j = 0; j < 8; ++j) {
      int e = e8 + j;
      Vt[e * PP + (s ^ (e & 56))] = vv[j];
    }
  }

  // scores: wave w's 16 Q-rows x 128 keys, fragments from global (L2-hot)
  {
    f32x4 acc[8] = {};
    const unsigned short* qrow = Pseqs + (size_t)(b * 2048 + l0 + w * 16 + frow) * NC + h * 64 + fk8;
#pragma unroll
    for (int ks = 0; ks < 2; ++ks) {
      bf16x8 a = *(const bf16x8*)(qrow + ks * 32);
#pragma unroll
      for (int nt = 0; nt < 8; ++nt) {
        bf16x8 bb = *(const bf16x8*)&Psmis[(size_t)(b * 128 + nt * 16 + frow) * NC + 512 + h * 64 + ks * 32 + fk8];
        acc[nt] = __builtin_amdgcn_mfma_f32_16x16x32_bf16(a, bb, acc[nt], 0, 0, 0);
      }
    }
#pragma unroll
    for (int nt = 0; nt < 8; ++nt)
#pragma unroll
      for (int r = 0; r < 4; ++r)
        Sc[(w * 16 + q * 4 + r) * PP + nt * 16 + frow] = f2bf(acc[nt][r]);
  }
  __syncthreads();

  // selection: lane owns 32 cols (seg = lane&3) of row (lane>>2); 16 rows per wave in one pass
  {
    int i = lane >> 2, seg = lane & 3;
    int row = w * 16 + i;
    unsigned short* rb = &Sc[row * PP + seg * 32];
    unsigned orig[16], B[16];
#pragma unroll
    for (int jb = 0; jb < 4; ++jb) {
      uint4 qv = *(const uint4*)(rb + jb * 8);
      orig[jb * 4 + 0] = qv.x; orig[jb * 4 + 1] = qv.y;
      orig[jb * 4 + 2] = qv.z; orig[jb * 4 + 3] = qv.w;
    }
#pragma unroll
    for (int j = 0; j < 16; ++j) {
      unsigned s = (orig[j] >> 15) & 0x00010001u;
      B[j] = orig[j] ^ (s * 0x7FFFu) ^ 0x80008000u;
    }
    TRANSPOSE16(B)
    // radix MSB->LSB; per-bit count over the row = popc + 2-step sum over its 4 lanes
    unsigned act = 0xFFFFFFFFu, gt = 0u, Tv = 0u;
    int rem = 32;
#pragma unroll
    for (int bit = 15; bit >= 0; --bit) {
      unsigned bm = B[15 - bit] & act;
      int c = __popc(bm);
      c += __shfl_xor(c, 1);
      c += __shfl_xor(c, 2);
      bool take = (c >= rem);
      act = take ? bm : (act ^ bm);
      gt = take ? gt : (gt | bm);
      rem = take ? rem : (rem - c);
      Tv = take ? (Tv | (1u << bit)) : Tv;
    }
    unsigned hT = (Tv & 0x8000u) ? (Tv ^ 0x8000u) : (Tv ^ 0xFFFFu);
    float vT = bf2f((unsigned short)hT);
    unsigned gtE = pos2elem(gt), actE = pos2elem(act);
    // tie budget: prefix of tie counts across the row's 4 segments (ascending col order)
    int pc = __popc(actE);
    int pr1 = __shfl_up(pc, 1);
    int inc = pc + ((seg >= 1) ? pr1 : 0);
    int pr2 = __shfl_up(inc, 2);
    inc += ((seg >= 2) ? pr2 : 0);
    int tie_pre = inc - pc;
    int budget = rem - tie_pre;
    budget = budget < 0 ? 0 : (budget > pc ? pc : budget);
    unsigned selT = 0u, m = actE;
    for (int t = 0; t < budget; ++t) { unsigned bb2 = m & (~m + 1u); selT |= bb2; m ^= bb2; }
    unsigned sel = gtE | selT;
    // unnormalized P written in place (aligned dword stores)
    unsigned* wb = (unsigned*)rb;
#pragma unroll
    for (int j = 0; j < 16; ++j) {
      unsigned d = orig[j];
      float v0 = bf2f((unsigned short)(d & 0xFFFFu));
      float v1 = bf2f((unsigned short)(d >> 16));
      float e0 = ((sel >> (2 * j)) & 1u) ? __expf((v0 - vT) * 0.125f) : 0.f;
      float e1 = ((sel >> (2 * j + 1)) & 1u) ? __expf((v1 - vT) * 0.125f) : 0.f;
      wb[j] = (unsigned)f2bf(e0) | ((unsigned)f2bf(e1) << 16);
    }
  }
  __syncthreads();

  // O_un = P_un[16x128] @ V[128x64]; den = P_un @ ones (extra MFMA column)
  f32x4 oacc[4] = {};
  f32x4 dacc = {};
  bf16x8 ones;
#pragma unroll
  for (int j = 0; j < 8; ++j) ones[j] = (__bf16)1.0f;
#pragma unroll
  for (int k0 = 0; k0 < 128; k0 += 32) {
    bf16x8 a = *(const bf16x8*)&Sc[(w * 16 + frow) * PP + k0 + fk8];
#pragma unroll
    for (int nt = 0; nt < 4; ++nt) {
      int e = nt * 16 + frow;
      bf16x8 bb = *(const bf16x8*)&Vt[e * PP + ((k0 + fk8) ^ (e & 56))];
      oacc[nt] = __builtin_amdgcn_mfma_f32_16x16x32_bf16(a, bb, oacc[nt], 0, 0, 0);
    }
    dacc = __builtin_amdgcn_mfma_f32_16x16x32_bf16(a, ones, dacc, 0, 0, 0);
  }
  float inv4[4];
#pragma unroll
  for (int r = 0; r < 4; ++r) inv4[r] = 1.f / dacc[r];
#pragma unroll
  for (int nt = 0; nt < 4; ++nt)
#pragma unroll
    for (int r = 0; r < 4; ++r)
      smil[(size_t)(b * 2048 + l0 + w * 16 + q * 4 + r) * 512 + h * 64 + nt * 16 + frow] =
          f2bf(oacc[nt][r] * inv4[r]);
}

// ---------------- fusion 2 scores: S2[bh][l 128][s 2048] bf16 ----------------
__global__ __launch_bounds__(256) void kf2scores(const unsigned short* __restrict__ Psmis,
                                                 const unsigned short* __restrict__ Pseqs,
                                                 unsigned short* __restrict__ S2) {
  __shared__ unsigned short As[128 * 32], Bs[128 * 32];
  int tid = threadIdx.x, lane = tid & 63, wave = tid >> 6;
  int st = blockIdx.x, bh = blockIdx.y;
  int b = bh >> 3, h = bh & 7;
  int s0 = st * 128;
  const unsigned short* Abase = Psmis + (size_t)b * 128 * NC + h * 64;
  const unsigned short* Bbase = Pseqs + (size_t)b * 2048 * NC + 512 + h * 64;
  f32x4 acc[4][4] = {};
  int wm = (wave >> 1) * 64, wn = (wave & 1) * 64;
  int frow = lane & 15, fk = (lane >> 4) * 8;
  for (int k0 = 0; k0 < 64; k0 += 32) {
    if (k0) __syncthreads();
#pragma unroll
    for (int j = 0; j < 2; ++j) {
      int ch = j * 256 + tid;
      int row = ch >> 2, kc = (ch & 3) * 8;
      gld16(Abase + (size_t)row * NC + k0 + kc, As + ch * 8);
      gld16(Bbase + (size_t)(s0 + row) * NC + k0 + kc, Bs + ch * 8);
    }
    __syncthreads();
    bf16x8 af[4], bfv[4];
#pragma unroll
    for (int mt = 0; mt < 4; ++mt) af[mt] = *(const bf16x8*)&As[(wm + mt * 16 + frow) * 32 + fk];
#pragma unroll
    for (int nt = 0; nt < 4; ++nt) bfv[nt] = *(const bf16x8*)&Bs[(wn + nt * 16 + frow) * 32 + fk];
#pragma unroll
    for (int mt = 0; mt < 4; ++mt)
#pragma unroll
      for (int nt = 0; nt < 4; ++nt)
        acc[mt][nt] = __builtin_amdgcn_mfma_f32_16x16x32_bf16(af[mt], bfv[nt], acc[mt][nt], 0, 0, 0);
  }
  int q = lane >> 4, c15 = lane & 15;
  unsigned short* outp = S2 + (size_t)bh * 128 * 2048;
#pragma unroll
  for (int mt = 0; mt < 4; ++mt)
#pragma unroll
    for (int nt = 0; nt < 4; ++nt)
#pragma unroll
      for (int r = 0; r < 4; ++r)
        outp[(size_t)(wm + mt * 16 + q * 4 + r) * 2048 + s0 + wn + nt * 16 + c15] = f2bf(acc[mt][nt][r]);
}

// ---------------- fusion 2 select: top-32 of 2048 per row via bit-plane radix select ----------------
__global__ __launch_bounds__(256) void kf2select(const unsigned short* __restrict__ S2,
                                                 const unsigned short* __restrict__ Pseqs,
                                                 float* __restrict__ seqs_out) {
  __shared__ float pS[4][32];
  __shared__ int   sS[4][32];
  int tid = threadIdx.x, lane = tid & 63, w = tid >> 6;
  int rid = blockIdx.x * 4 + w;
  int l = rid & 127, bh = rid >> 7;
  int h = bh & 7, b = bh >> 3;
  const unsigned short* rowp = S2 + (size_t)rid * 2048;

  unsigned B[16];
  const uint4* p4 = (const uint4*)(rowp + lane * 32);
#pragma unroll
  for (int i = 0; i < 4; ++i) {
    uint4 qv = p4[i];
    B[i * 4 + 0] = qv.x; B[i * 4 + 1] = qv.y; B[i * 4 + 2] = qv.z; B[i * 4 + 3] = qv.w;
  }
#pragma unroll
  for (int i = 0; i < 16; ++i) {
    unsigned s = (B[i] >> 15) & 0x00010001u;
    B[i] = B[i] ^ (s * 0x7FFFu) ^ 0x80008000u;
  }
  TRANSPOSE16(B)
  unsigned act = 0xFFFFFFFFu, gt = 0u, Tv = 0u;
  int rem = 32;
#pragma unroll
  for (int bit = 15; bit >= 0; --bit) {
    unsigned bm = B[15 - bit] & act;
    int c = __popc(bm);
#pragma unroll
    for (int d = 1; d < 64; d <<= 1) c += __shfl_xor(c, d);
    bool take = (c >= rem);
    unsigned actx = act ^ bm;
    act = take ? bm : actx;
    gt = take ? gt : (gt | bm);
    rem = take ? rem : (rem - c);
    Tv = take ? (Tv | (1u << bit)) : Tv;
  }
  unsigned hT = (Tv & 0x8000u) ? (Tv ^ 0x8000u) : (Tv ^ 0xFFFFu);
  float vT = bf2f((unsigned short)hT);

  gt = pos2elem(gt);
  act = pos2elem(act);

  int pc_tie = __popc(act);
  int inc = pc_tie;
#pragma unroll
  for (int d = 1; d < 64; d <<= 1) { int y = __shfl_up(inc, d); if (lane >= d) inc += y; }
  int tie_pre = inc - pc_tie;
  int budget = rem - tie_pre;
  budget = budget < 0 ? 0 : (budget > pc_tie ? pc_tie : budget);
  int total_lane = __popc(gt) + budget;
  int inc2 = total_lane;
#pragma unroll
  for (int d = 1; d < 64; d <<= 1) { int y = __shfl_up(inc2, d); if (lane >= d) inc2 += y; }
  int slot = inc2 - total_lane;

  float lsum = 0.f;
  unsigned m = gt;
  while (m) {
    int e = __builtin_ctz(m); m &= m - 1;
    int gidx = (lane << 5) + e;
    float v = bf2f(rowp[gidx]);
    float ev = __expf((v - vT) * 0.125f);
    pS[w][slot] = ev; sS[w][slot] = gidx; ++slot; lsum += ev;
  }
  m = act;
  for (int taken = 0; taken < budget; ++taken) {
    int e = __builtin_ctz(m); m &= m - 1;
    int gidx = (lane << 5) + e;
    float v = bf2f(rowp[gidx]);
    float ev = __expf((v - vT) * 0.125f);
    pS[w][slot] = ev; sS[w][slot] = gidx; ++slot; lsum += ev;
  }
  float den = lsum;
#pragma unroll
  for (int d = 1; d < 64; d <<= 1) den += __shfl_xor(den, d);

  float acc = 0.f;
  const unsigned short* Vb = Pseqs + (size_t)(b * 2048) * NC + 1024 + h * 64 + lane;
#pragma unroll 8
  for (int t = 0; t < 32; ++t) {
    float pv = pS[w][t];
    int s = sS[w][t];
    acc += pv * bf2f(Vb[(size_t)s * NC]);
  }
  seqs_out[(size_t)(b * 128 + l) * 512 + h * 64 + lane] = acc / den;
}

// ---------------- pooling ----------------
__device__ __forceinline__ float dot8(uint4 pk, const float* w) {
  float s = bf2f((unsigned short)(pk.x & 0xFFFFu)) * w[0] + bf2f((unsigned short)(pk.x >> 16)) * w[1];
  s += bf2f((unsigned short)(pk.y & 0xFFFFu)) * w[2] + bf2f((unsigned short)(pk.y >> 16)) * w[3];
  s += bf2f((unsigned short)(pk.z & 0xFFFFu)) * w[4] + bf2f((unsigned short)(pk.z >> 16)) * w[5];
  s += bf2f((unsigned short)(pk.w & 0xFFFFu)) * w[6] + bf2f((unsigned short)(pk.w >> 16)) * w[7];
  return s;
}

__global__ __launch_bounds__(256) void kpool1a(const unsigned short* __restrict__ x,
                                               const float* __restrict__ wp, const float* __restrict__ bp,
                                               float* __restrict__ logits) {
  int tid = threadIdx.x, lane = tid & 63, wave = tid >> 6;
  int r = blockIdx.x * 4 + wave;
  uint4 pk = *(const uint4*)(x + (size_t)r * 512 + lane * 8);
  float acc = dot8(pk, wp + lane * 8);
#pragma unroll
  for (int d = 1; d < 64; d <<= 1) acc += __shfl_xor(acc, d);
  if (lane == 0) logits[r] = acc + bp[0];
}

// grid 256: b = bi>>4, ls = (bi>>1)&7, colhalf = bi&1
__global__ __launch_bounds__(256) void kpool1b(const unsigned short* __restrict__ x,
                                               const float* __restrict__ logits,
                                               float* __restrict__ aout, float* __restrict__ pp) {
  __shared__ float red[256];
  __shared__ float aS[256];
  int t = threadIdx.x;
  int b = blockIdx.x >> 4, ls = (blockIdx.x >> 1) & 7, cj = blockIdx.x & 1;
  const float* lg = logits + b * 2048;
  float lm = -FLT_MAX;
  for (int j = t; j < 2048; j += 256) lm = fmaxf(lm, lg[j]);
  red[t] = lm; __syncthreads();
  for (int s = 128; s > 0; s >>= 1) { if (t < s) red[t] = fmaxf(red[t], red[t + s]); __syncthreads(); }
  float M = red[0]; __syncthreads();
  float sm = 0.f;
  for (int j = t; j < 2048; j += 256) sm += __expf(lg[j] - M);
  red[t] = sm; __syncthreads();
  for (int s = 128; s > 0; s >>= 1) { if (t < s) red[t] += red[t + s]; __syncthreads(); }
  float D = red[0];
  int l0 = ls * 256;
  float a = __expf(lg[l0 + t] - M) / D;
  aS[t] = a;
  if (cj == 0) aout[b * 2048 + l0 + t] = a;
  __syncthreads();
  int col = cj * 256 + t;
  float acc0 = 0.f;
  const unsigned short* xb = x + ((size_t)b * 2048 + l0) * 512 + col;
#pragma unroll 8
  for (int ll = 0; ll < 256; ++ll) acc0 += aS[ll] * bf2f(xb[(size_t)ll * 512]);
  pp[(size_t)(b * 8 + ls) * 512 + col] = acc0;
}

__global__ __launch_bounds__(256) void kpool2(const float* __restrict__ x,
                                              const float* __restrict__ wp, const float* __restrict__ bp,
                                              float* __restrict__ a2out, float* __restrict__ pooled2) {
  __shared__ float lgS[128];
  int t = threadIdx.x, lane = t & 63, wave = t >> 6;
  int b = blockIdx.x;
  for (int i = 0; i < 32; ++i) {
    int row = wave * 32 + i;
    const float* xp = x + (size_t)(b * 128 + row) * 512;
    float acc = 0.f;
#pragma unroll
    for (int j = 0; j < 8; ++j) acc += xp[lane + 64 * j] * wp[lane + 64 * j];
#pragma unroll
    for (int d = 1; d < 64; d <<= 1) acc += __shfl_xor(acc, d);
    if (lane == 0) lgS[row] = acc + bp[0];
  }
  __syncthreads();
  if (wave == 0) {
    float a0 = lgS[lane], a1 = lgS[64 + lane];
    float m = fmaxf(a0, a1);
#pragma unroll
    for (int d = 1; d < 64; d <<= 1) m = fmaxf(m, __shfl_xor(m, d));
    float e0 = __expf(a0 - m), e1 = __expf(a1 - m);
    float sden = e0 + e1;
#pragma unroll
    for (int d = 1; d < 64; d <<= 1) sden += __shfl_xor(sden, d);
    a0 = e0 / sden; a1 = e1 / sden;
    lgS[lane] = a0; lgS[64 + lane] = a1;
    a2out[b * 128 + lane] = a0;
    a2out[b * 128 + 64 + lane] = a1;
  }
  __syncthreads();
  float acc0 = 0.f, acc1 = 0.f;
#pragma unroll 4
  for (int row = 0; row < 128; ++row) {
    float av = lgS[row];
    const float* xp = x + (size_t)(b * 128 + row) * 512;
    acc0 += av * xp[t];
    acc1 += av * xp[t + 256];
  }
  pooled2[(size_t)b * 512 + t] = acc0;
  pooled2[(size_t)b * 512 + t + 256] = acc1;
}

// ---------------- head ----------------
__global__ __launch_bounds__(256) void kemb(const float* __restrict__ pp, const float* __restrict__ pooled2,
                                            float* __restrict__ embo, float* __restrict__ embws) {
  __shared__ float red[256];
  int t = threadIdx.x, b = blockIdx.x;
  float pre[4];
#pragma unroll
  for (int qq = 0; qq < 4; ++qq) {
    int c = qq * 256 + t;
    float s;
    if (c < 512) {
      s = 0.f;
      for (int lsl = 0; lsl < 8; ++lsl) s += pp[(size_t)(b * 8 + lsl) * 512 + c];
    } else {
      s = pooled2[(size_t)b * 512 + (c - 512)];
    }
    pre[qq] = s;
  }
  float ssq = pre[0] * pre[0] + pre[1] * pre[1] + pre[2] * pre[2] + pre[3] * pre[3];
  red[t] = ssq; __syncthreads();
  for (int s2 = 128; s2 > 0; s2 >>= 1) { if (t < s2) red[t] += red[t + s2]; __syncthreads(); }
  float inv = 1.f / fmaxf(sqrtf(red[0]), 1e-12f);
#pragma unroll
  for (int qq = 0; qq < 4; ++qq) {
    int c = qq * 256 + t;
    float e = pre[qq] * inv;
    embo[(size_t)b * 1024 + c] = e;
    embws[(size_t)b * 1024 + c] = e;
  }
}

__global__ __launch_bounds__(256) void kmlp(const float* __restrict__ in, const float* __restrict__ W,
                                            const float* __restrict__ bias, float* __restrict__ out,
                                            int IN, int ON) {
  __shared__ float e[1024];
  int t = threadIdx.x;
  int chunks = ON >> 8;
  int b = blockIdx.x / chunks, jc = blockIdx.x % chunks;
  for (int q = t; q < IN; q += 256) e[q] = in[(size_t)b * IN + q];
  __syncthreads();
  int j = jc * 256 + t;
  float acc = bias[j];
#pragma unroll 8
  for (int i = 0; i < IN; ++i) acc += e[i] * W[(size_t)i * ON + j];
  out[(size_t)b * ON + j] = fmaxf(acc, 0.f);
}

__global__ void kout(const float* __restrict__ h2, const float* __restrict__ W3, const float* __restrict__ b3,
                     float* __restrict__ outp) {
  int b = blockIdx.x, lane = threadIdx.x;
  float acc = 0.f;
#pragma unroll
  for (int j = 0; j < 8; ++j) acc += h2[(size_t)b * 512 + lane + 64 * j] * W3[lane + 64 * j];
#pragma unroll
  for (int d = 1; d < 64; d <<= 1) acc += __shfl_xor(acc, d);
  if (lane == 0) outp[b] = acc + b3[0];
}

// ---------------- launch ----------------
extern "C" void kernel_launch(void* const* d_in, const int* in_sizes, int n_in,
                              void* d_out, int out_size, void* d_ws, size_t ws_size,
                              hipStream_t stream) {
  const float* seqs = (const float*)d_in[0];
  const float* smis = (const float*)d_in[1];
  const float* Wq = (const float*)d_in[2];
  const float* bq = (const float*)d_in[3];
  const float* Wk = (const float*)d_in[4];
  const float* bk = (const float*)d_in[5];
  const float* Wv = (const float*)d_in[6];
  const float* bv = (const float*)d_in[7];
  const float* wp = (const float*)d_in[8];
  const float* bp = (const float*)d_in[9];
  const float* W1 = (const float*)d_in[10];
  const float* b1 = (const float*)d_in[11];
  const float* W2 = (const float*)d_in[12];
  const float* b2 = (const float*)d_in[13];
  const float* W3 = (const float*)d_in[14];
  const float* b3 = (const float*)d_in[15];
  float* out = (float*)d_out;
  char* ws = (char*)d_ws;

  float* nrm_s = (float*)(ws + WS_NRM_S);
  float* nrm_m = (float*)(ws + WS_NRM_M);
  float* part_s = (float*)(ws + WS_PART);
  float* part_m = (float*)(ws + WS_PARTM);
  float* bcat = (float*)(ws + WS_BCAT);
  float* log1 = (float*)(ws + WS_LOG1);
  float* pp1 = (float*)(ws + WS_PP1);
  float* pooled2 = (float*)(ws + WS_POOL2);
  float* embws = (float*)(ws + WS_EMB);
  float* h1 = (float*)(ws + WS_H1);
  float* h2 = (float*)(ws + WS_H2);
  unsigned short* wct = (unsigned short*)(ws + WS_WCT);
  unsigned short* smis_nb = (unsigned short*)(ws + WS_SMISNB);
  unsigned short* Psmis = (unsigned short*)(ws + WS_PSMIS);
  float* seqs_out = (float*)(ws + WS_SEQSOUT);
  unsigned short* seqs_nb = (unsigned short*)(ws + WS_SEQSNB);
  unsigned short* Pseqs = (unsigned short*)(ws + WS_PSEQS);
  unsigned short* smil = (unsigned short*)(ws + WS_SMILOUT);
  unsigned short* S2 = (unsigned short*)(ws + WS_S2);

  // 1. column norms (part buffers alias Pseqs region; consumed before kgemm writes it)
  knorm_part<<<dim3(64, 16), 128, 0, stream>>>(seqs, part_s, 32, 64);
  knorm_part<<<dim3(4, 16), 128, 0, stream>>>(smis, part_m, 32, 4);
  knorm_fin<<<dim3(32), 256, 0, stream>>>(part_s, nrm_s, 64);
  knorm_fin<<<dim3(32), 256, 0, stream>>>(part_m, nrm_m, 4);
  // 2. normalize + cast to bf16
  kcast<<<dim3(16384), 256, 0, stream>>>(seqs, nrm_s, seqs_nb, 20, 16 * 2048 * 512);
  kcast<<<dim3(1024), 256, 0, stream>>>(smis, nrm_m, smis_nb, 16, 16 * 128 * 512);
  // 3. weight prep
  kprepw<<<dim3(16, 16, 3), 256, 0, stream>>>(Wq, Wk, Wv, wct);
  kprepb<<<dim3(6), 256, 0, stream>>>(bq, bk, bv, bcat);
  // 4. fused QKV projections (1D grid, XCD remap, A-dbuf + direct-global B frags)
  kgemm<<<dim3(3072), 256, 0, stream>>>(seqs_nb, wct, bcat, Pseqs, 512, NC, 12);
  kgemm<<<dim3(192), 256, 0, stream>>>(smis_nb, wct, bcat, Psmis, 512, NC, 12);
  // 5. fusion 1 attention (writes smil, aliases dead seqs_nb)
  kfusion1<<<dim3(32, 8, 16), 256, 0, stream>>>(Pseqs, Psmis, smil);
  // 6. pool 1
  kpool1a<<<dim3(8192), 256, 0, stream>>>(smil, wp, bp, log1);
  kpool1b<<<dim3(256), 256, 0, stream>>>(smil, log1, out + OUT_A1, pp1);
  // 7. fusion 2
  kf2scores<<<dim3(16, 128), 256, 0, stream>>>(Psmis, Pseqs, S2);
  kf2select<<<dim3(4096), 256, 0, stream>>>(S2, Pseqs, seqs_out);
  kpool2<<<dim3(16), 256, 0, stream>>>(seqs_out, wp, bp, out + OUT_A2, pooled2);
  // 8. head
  kemb<<<dim3(16), 256, 0, stream>>>(pp1, pooled2, out + OUT_EMB, embws);
  kmlp<<<dim3(64), 256, 0, stream>>>(embws, W1, b1, h1, 1024, 1024);
  kmlp<<<dim3(32), 256, 0, stream>>>(h1, W2, b2, h2, 1024, 512);
  kout<<<dim3(16), 64, 0, stream>>>(h2, W3, b3, out + OUT_OUT);
}

// Round 11
// 567.030 us; speedup vs baseline: 1.0847x; 1.0847x over previous
//
#include <hip/hip_runtime.h>
#include <cfloat>
#include <cstdint>

// ---------------- problem constants ----------------
#define NC 1536   // 3*H concatenated projection width

// d_out float offsets: emb[16,1024] | out[16] | smiles_attn_pool[16,2048] | seqs_attn_pool[16,128]
#define OUT_EMB 0
#define OUT_OUT 16384
#define OUT_A1  16400
#define OUT_A2  49168

// ws byte offsets
#define WS_NRM_S   0u
#define WS_NRM_M   32768u
#define WS_BCAT    360448u
#define WS_LOG1    366592u
#define WS_PP1     505856u
#define WS_POOL2   768000u
#define WS_EMB     800768u
#define WS_H1      866304u
#define WS_H2      931840u
#define WS_WCT     1048576u
#define WS_SMISNB  2621440u
#define WS_PSMIS   4718592u
#define WS_SEQSOUT 11010048u
#define WS_SEQSNB  15204352u
#define WS_PSEQS   48758784u
#define WS_SMILOUT WS_SEQSNB          // seqs_nb dead after GEMM1; reuse for smiles_out
#define WS_S2      149422080u          // ws total need ~216.5 MB
// norm partials are consumed before Pseqs is written -> alias that region
#define WS_PART    WS_PSEQS
#define WS_PARTM   (WS_PSEQS + 2097152u)

typedef float f32x4 __attribute__((ext_vector_type(4)));
typedef __bf16 bf16x8 __attribute__((ext_vector_type(8)));
typedef unsigned short u16x8 __attribute__((ext_vector_type(8)));

__device__ __forceinline__ float bf2f(unsigned short h) {
  return __uint_as_float(((unsigned int)h) << 16);
}
__device__ __forceinline__ unsigned short f2bf(float f) {
  unsigned int u = __float_as_uint(f);
  return (unsigned short)((u + 0x7FFFu + ((u >> 16) & 1u)) >> 16);
}
__device__ __forceinline__ void gld16(const unsigned short* g, unsigned short* l) {
  __builtin_amdgcn_global_load_lds(
      (__attribute__((address_space(1))) unsigned int*)(uintptr_t)g,
      (__attribute__((address_space(3))) unsigned int*)l, 16, 0, 0);
}

// position-space mask -> element-space mask for the anti-diagonal transpose layout:
// element 2c sits at position 15-c (low half), element 2c+1 at position 31-c (high half)
__device__ __forceinline__ unsigned pos2elem(unsigned m) {
  unsigned lo = __brev(m & 0xFFFFu) >> 16;   // bit i = m bit (15-i)
  unsigned hi = __brev(m >> 16) >> 16;       // bit i = m bit (31-i)
  lo = (lo | (lo << 8)) & 0x00FF00FFu;
  lo = (lo | (lo << 4)) & 0x0F0F0F0Fu;
  lo = (lo | (lo << 2)) & 0x33333333u;
  lo = (lo | (lo << 1)) & 0x55555555u;
  hi = (hi | (hi << 8)) & 0x00FF00FFu;
  hi = (hi | (hi << 4)) & 0x0F0F0F0Fu;
  hi = (hi | (hi << 2)) & 0x33333333u;
  hi = (hi | (hi << 1)) & 0x55555555u;
  return lo | (hi << 1);
}

#define TRANSPOSE16(B)                                                                             \
  {                                                                                                \
    unsigned t;                                                                                    \
    t = (B[0] ^ (B[8] >> 8)) & 0x00FF00FFu; B[0] ^= t; B[8] ^= (t << 8);                           \
    t = (B[1] ^ (B[9] >> 8)) & 0x00FF00FFu; B[1] ^= t; B[9] ^= (t << 8);                           \
    t = (B[2] ^ (B[10] >> 8)) & 0x00FF00FFu; B[2] ^= t; B[10] ^= (t << 8);                         \
    t = (B[3] ^ (B[11] >> 8)) & 0x00FF00FFu; B[3] ^= t; B[11] ^= (t << 8);                         \
    t = (B[4] ^ (B[12] >> 8)) & 0x00FF00FFu; B[4] ^= t; B[12] ^= (t << 8);                         \
    t = (B[5] ^ (B[13] >> 8)) & 0x00FF00FFu; B[5] ^= t; B[13] ^= (t << 8);                         \
    t = (B[6] ^ (B[14] >> 8)) & 0x00FF00FFu; B[6] ^= t; B[14] ^= (t << 8);                         \
    t = (B[7] ^ (B[15] >> 8)) & 0x00FF00FFu; B[7] ^= t; B[15] ^= (t << 8);                         \
    t = (B[0] ^ (B[4] >> 4)) & 0x0F0F0F0Fu; B[0] ^= t; B[4] ^= (t << 4);                           \
    t = (B[1] ^ (B[5] >> 4)) & 0x0F0F0F0Fu; B[1] ^= t; B[5] ^= (t << 4);                           \
    t = (B[2] ^ (B[6] >> 4)) & 0x0F0F0F0Fu; B[2] ^= t; B[6] ^= (t << 4);                           \
    t = (B[3] ^ (B[7] >> 4)) & 0x0F0F0F0Fu; B[3] ^= t; B[7] ^= (t << 4);                           \
    t = (B[8] ^ (B[12] >> 4)) & 0x0F0F0F0Fu; B[8] ^= t; B[12] ^= (t << 4);                         \
    t = (B[9] ^ (B[13] >> 4)) & 0x0F0F0F0Fu; B[9] ^= t; B[13] ^= (t << 4);                         \
    t = (B[10] ^ (B[14] >> 4)) & 0x0F0F0F0Fu; B[10] ^= t; B[14] ^= (t << 4);                       \
    t = (B[11] ^ (B[15] >> 4)) & 0x0F0F0F0Fu; B[11] ^= t; B[15] ^= (t << 4);                       \
    t = (B[0] ^ (B[2] >> 2)) & 0x33333333u; B[0] ^= t; B[2] ^= (t << 2);                           \
    t = (B[1] ^ (B[3] >> 2)) & 0x33333333u; B[1] ^= t; B[3] ^= (t << 2);                           \
    t = (B[4] ^ (B[6] >> 2)) & 0x33333333u; B[4] ^= t; B[6] ^= (t << 2);                           \
    t = (B[5] ^ (B[7] >> 2)) & 0x33333333u; B[5] ^= t; B[7] ^= (t << 2);                           \
    t = (B[8] ^ (B[10] >> 2)) & 0x33333333u; B[8] ^= t; B[10] ^= (t << 2);                         \
    t = (B[9] ^ (B[11] >> 2)) & 0x33333333u; B[9] ^= t; B[11] ^= (t << 2);                         \
    t = (B[12] ^ (B[14] >> 2)) & 0x33333333u; B[12] ^= t; B[14] ^= (t << 2);                       \
    t = (B[13] ^ (B[15] >> 2)) & 0x33333333u; B[13] ^= t; B[15] ^= (t << 2);                       \
    t = (B[0] ^ (B[1] >> 1)) & 0x55555555u; B[0] ^= t; B[1] ^= (t << 1);                           \
    t = (B[2] ^ (B[3] >> 1)) & 0x55555555u; B[2] ^= t; B[3] ^= (t << 1);                           \
    t = (B[4] ^ (B[5] >> 1)) & 0x55555555u; B[4] ^= t; B[5] ^= (t << 1);                           \
    t = (B[6] ^ (B[7] >> 1)) & 0x55555555u; B[6] ^= t; B[7] ^= (t << 1);                           \
    t = (B[8] ^ (B[9] >> 1)) & 0x55555555u; B[8] ^= t; B[9] ^= (t << 1);                           \
    t = (B[10] ^ (B[11] >> 1)) & 0x55555555u; B[10] ^= t; B[11] ^= (t << 1);                       \
    t = (B[12] ^ (B[13] >> 1)) & 0x55555555u; B[12] ^= t; B[13] ^= (t << 1);                       \
    t = (B[14] ^ (B[15] >> 1)) & 0x55555555u; B[14] ^= t; B[15] ^= (t << 1);                       \
  }

// ---------------- column-wise l2 norms (axis=1) ----------------
// thread t owns 4 consecutive cols (float4); block owns a row-slab -> full MLP, coalesced.
__global__ __launch_bounds__(128) void knorm_part(const float* __restrict__ x, float* __restrict__ part,
                                                  int SL, int NS) {
  int ls = blockIdx.x, b = blockIdx.y, t = threadIdx.x;
  const float* xp = x + ((size_t)b * NS + ls) * SL * 512 + t * 4;
  float ax = 0.f, ay = 0.f, az = 0.f, aw = 0.f;
  for (int l = 0; l < SL; ++l) {
    float4 v = *(const float4*)(xp + (size_t)l * 512);
    ax += v.x * v.x; ay += v.y * v.y; az += v.z * v.z; aw += v.w * v.w;
  }
  float4 r = {ax, ay, az, aw};
  *(float4*)(part + ((size_t)(b * NS + ls)) * 512 + t * 4) = r;
}

// grid 32 x 256: bh = b*2 + colhalf
__global__ __launch_bounds__(256) void knorm_fin(const float* __restrict__ part, float* __restrict__ inv, int NS) {
  int bh = blockIdx.x, t = threadIdx.x;
  int b = bh >> 1, col = (bh & 1) * 256 + t;
  float s = 0.f;
  for (int j = 0; j < NS; ++j) s += part[((size_t)(b * NS + j)) * 512 + col];
  inv[(size_t)b * 512 + col] = 1.f / fmaxf(sqrtf(s), 1e-12f);
}

__global__ __launch_bounds__(256) void kcast(const float* __restrict__ x, const float* __restrict__ inv,
                                             unsigned short* __restrict__ o, int shiftB, int total) {
  int i4 = (blockIdx.x * 256 + threadIdx.x) * 4;
  if (i4 >= total) return;
  int b = i4 >> shiftB;
  float4 v = *(const float4*)(x + i4);
  float4 nv = *(const float4*)(inv + (b << 9) + (i4 & 511));
  ushort4 r;
  r.x = f2bf(v.x * nv.x); r.y = f2bf(v.y * nv.y);
  r.z = f2bf(v.z * nv.z); r.w = f2bf(v.w * nv.w);
  *(ushort4*)(o + i4) = r;
}

// ---------------- weight prep: WcatT[1536][512] bf16 (B^T layout), bcat ----------------
__global__ __launch_bounds__(256) void kprepw(const float* __restrict__ Wq, const float* __restrict__ Wk,
                                              const float* __restrict__ Wv, unsigned short* __restrict__ WT) {
  __shared__ float T[32][33];
  int ti = blockIdx.x, tj = blockIdx.y, m = blockIdx.z;
  const float* W = m == 0 ? Wq : (m == 1 ? Wk : Wv);
  int c = threadIdx.x & 31, r0 = threadIdx.x >> 5;
#pragma unroll
  for (int j = 0; j < 4; ++j) {
    int r = r0 + j * 8;
    T[r][c] = W[(size_t)(ti * 32 + r) * 512 + tj * 32 + c];
  }
  __syncthreads();
#pragma unroll
  for (int j = 0; j < 4; ++j) {
    int r = r0 + j * 8;
    WT[(size_t)(m * 512 + tj * 32 + r) * 512 + ti * 32 + c] = f2bf(T[c][r]);
  }
}

__global__ void kprepb(const float* bq, const float* bk, const float* bv, float* bcat) {
  int i = blockIdx.x * 256 + threadIdx.x;
  if (i >= 1536) return;
  bcat[i] = i < 512 ? bq[i] : (i < 1024 ? bk[i - 512] : bv[i - 1024]);
}

// ---------------- bf16 MFMA GEMM: C[M,N] = A[M,K] @ Bt[N,K]^T + bias ----------------
// v3 (best measured): LDS double-buffer for A and B (1 barrier/K-iter, DMA prefetch in
// flight across the MFMA block) + in-kernel XCD remap (id&7 = XCD; per-XCD j walks n
// FAST so each A-tile's NT uses are time-contiguous on one XCD -> A L2-resident).
// NOTE (R10 lesson): register-level global B prefetch regressed — __syncthreads drains
// vmcnt(0), killing cross-barrier register prefetches, and per-lane row loads uncoalesce.
__global__ __launch_bounds__(256) void kgemm(const unsigned short* __restrict__ A,
                                             const unsigned short* __restrict__ Bt,
                                             const float* __restrict__ bias,
                                             unsigned short* __restrict__ C,
                                             int K, int N, int NT) {
  __shared__ unsigned short As[2][128 * 32], Bs[2][128 * 32];
  int tid = threadIdx.x, lane = tid & 63, wave = tid >> 6;
  int id = blockIdx.x;
  int xcd = id & 7, j = id >> 3;
  int mloc = j / NT, n = j - mloc * NT;
  int m0 = (mloc * 8 + xcd) * 128, n0 = n * 128;
  f32x4 acc[4][4] = {};
  int wm = (wave >> 1) * 64, wn = (wave & 1) * 64;
  int frow = lane & 15, fk = (lane >> 4) * 8;

  auto stage = [&](int buf, int k0) {
#pragma unroll
    for (int jj = 0; jj < 2; ++jj) {
      int ch = jj * 256 + tid;
      int row = ch >> 2, kc = (ch & 3) * 8;
      gld16(A + (size_t)(m0 + row) * K + k0 + kc, As[buf] + ch * 8);
      gld16(Bt + (size_t)(n0 + row) * K + k0 + kc, Bs[buf] + ch * 8);
    }
  };

  stage(0, 0);
  __syncthreads();
  int nk = K >> 5;
  for (int it = 0; it < nk; ++it) {
    int cur = it & 1;
    if (it + 1 < nk) stage(cur ^ 1, (it + 1) << 5);   // prefetch next tile; lands during MFMAs
    bf16x8 af[4], bfv[4];
#pragma unroll
    for (int mt = 0; mt < 4; ++mt) af[mt] = *(const bf16x8*)&As[cur][(wm + mt * 16 + frow) * 32 + fk];
#pragma unroll
    for (int nt = 0; nt < 4; ++nt) bfv[nt] = *(const bf16x8*)&Bs[cur][(wn + nt * 16 + frow) * 32 + fk];
#pragma unroll
    for (int mt = 0; mt < 4; ++mt)
#pragma unroll
      for (int nt = 0; nt < 4; ++nt)
        acc[mt][nt] = __builtin_amdgcn_mfma_f32_16x16x32_bf16(af[mt], bfv[nt], acc[mt][nt], 0, 0, 0);
    __syncthreads();   // publishes prefetch (vmcnt drain overlapped by the 16 MFMAs above)
  }
  int q = lane >> 4, c15 = lane & 15;
#pragma unroll
  for (int mt = 0; mt < 4; ++mt)
#pragma unroll
    for (int nt = 0; nt < 4; ++nt) {
      int col = n0 + wn + nt * 16 + c15;
      float bv = bias ? bias[col] : 0.f;
#pragma unroll
      for (int r = 0; r < 4; ++r) {
        int row = m0 + wm + mt * 16 + q * 4 + r;
        C[(size_t)row * N + col] = f2bf(acc[mt][nt][r] + bv);
      }
    }
}

// ---------------- fusion 1: Q=seqs(2048) K,V=smis(128); top-32 of 128 ----------------
// v4: 4 waves/block; per-lane bit-plane radix (16 rows selected per wave in one pass),
// XOR-swizzled Vt, ones-column MFMA denominator.
__global__ __launch_bounds__(256) void kfusion1(const unsigned short* __restrict__ Pseqs,
                                                const unsigned short* __restrict__ Psmis,
                                                unsigned short* __restrict__ smil) {
  constexpr int PP = 136;                 // halfword pitch, rows 16B-aligned
  __shared__ unsigned short Sc[64 * PP];  // scores, then unnormalized P (bf16)
  __shared__ unsigned short Vt[64 * PP];  // V^T [e][s ^ (e&56)] (swizzled)
  int tid = threadIdx.x, lane = tid & 63, w = tid >> 6;
  int lt = blockIdx.x, h = blockIdx.y, b = blockIdx.z;
  int l0 = lt * 64;
  int frow = lane & 15, q = lane >> 4, fk8 = q * 8;

  // stage V^T, XOR swizzle on s-blocks
  for (int ch = tid; ch < 1024; ch += 256) {
    int s = ch >> 3, e8 = (ch & 7) * 8;
    u16x8 vv = *(const u16x8*)&Psmis[(size_t)(b * 128 + s) * NC + 1024 + h * 64 + e8];
#pragma unroll
    for (int j = 0; j < 8; ++j) {
      int e = e8 + j;
      Vt[e * PP + (s ^ (e & 56))] = vv[j];
    }
  }

  // scores: wave w's 16 Q-rows x 128 keys, fragments from global (L2-hot)
  {
    f32x4 acc[8] = {};
    const unsigned short* qrow = Pseqs + (size_t)(b * 2048 + l0 + w * 16 + frow) * NC + h * 64 + fk8;
#pragma unroll
    for (int ks = 0; ks < 2; ++ks) {
      bf16x8 a = *(const bf16x8*)(qrow + ks * 32);
#pragma unroll
      for (int nt = 0; nt < 8; ++nt) {
        bf16x8 bb = *(const bf16x8*)&Psmis[(size_t)(b * 128 + nt * 16 + frow) * NC + 512 + h * 64 + ks * 32 + fk8];
        acc[nt] = __builtin_amdgcn_mfma_f32_16x16x32_bf16(a, bb, acc[nt], 0, 0, 0);
      }
    }
#pragma unroll
    for (int nt = 0; nt < 8; ++nt)
#pragma unroll
      for (int r = 0; r < 4; ++r)
        Sc[(w * 16 + q * 4 + r) * PP + nt * 16 + frow] = f2bf(acc[nt][r]);
  }
  __syncthreads();

  // selection: lane owns 32 cols (seg = lane&3) of row (lane>>2); 16 rows per wave in one pass
  {
    int i = lane >> 2, seg = lane & 3;
    int row = w * 16 + i;
    unsigned short* rb = &Sc[row * PP + seg * 32];
    unsigned orig[16], B[16];
#pragma unroll
    for (int jb = 0; jb < 4; ++jb) {
      uint4 qv = *(const uint4*)(rb + jb * 8);
      orig[jb * 4 + 0] = qv.x; orig[jb * 4 + 1] = qv.y;
      orig[jb * 4 + 2] = qv.z; orig[jb * 4 + 3] = qv.w;
    }
#pragma unroll
    for (int j = 0; j < 16; ++j) {
      unsigned s = (orig[j] >> 15) & 0x00010001u;
      B[j] = orig[j] ^ (s * 0x7FFFu) ^ 0x80008000u;
    }
    TRANSPOSE16(B)
    // radix MSB->LSB; per-bit count over the row = popc + 2-step sum over its 4 lanes
    unsigned act = 0xFFFFFFFFu, gt = 0u, Tv = 0u;
    int rem = 32;
#pragma unroll
    for (int bit = 15; bit >= 0; --bit) {
      unsigned bm = B[15 - bit] & act;
      int c = __popc(bm);
      c += __shfl_xor(c, 1);
      c += __shfl_xor(c, 2);
      bool take = (c >= rem);
      act = take ? bm : (act ^ bm);
      gt = take ? gt : (gt | bm);
      rem = take ? rem : (rem - c);
      Tv = take ? (Tv | (1u << bit)) : Tv;
    }
    unsigned hT = (Tv & 0x8000u) ? (Tv ^ 0x8000u) : (Tv ^ 0xFFFFu);
    float vT = bf2f((unsigned short)hT);
    unsigned gtE = pos2elem(gt), actE = pos2elem(act);
    // tie budget: prefix of tie counts across the row's 4 segments (ascending col order)
    int pc = __popc(actE);
    int pr1 = __shfl_up(pc, 1);
    int inc = pc + ((seg >= 1) ? pr1 : 0);
    int pr2 = __shfl_up(inc, 2);
    inc += ((seg >= 2) ? pr2 : 0);
    int tie_pre = inc - pc;
    int budget = rem - tie_pre;
    budget = budget < 0 ? 0 : (budget > pc ? pc : budget);
    unsigned selT = 0u, m = actE;
    for (int t = 0; t < budget; ++t) { unsigned bb2 = m & (~m + 1u); selT |= bb2; m ^= bb2; }
    unsigned sel = gtE | selT;
    // unnormalized P written in place (aligned dword stores)
    unsigned* wb = (unsigned*)rb;
#pragma unroll
    for (int j = 0; j < 16; ++j) {
      unsigned d = orig[j];
      float v0 = bf2f((unsigned short)(d & 0xFFFFu));
      float v1 = bf2f((unsigned short)(d >> 16));
      float e0 = ((sel >> (2 * j)) & 1u) ? __expf((v0 - vT) * 0.125f) : 0.f;
      float e1 = ((sel >> (2 * j + 1)) & 1u) ? __expf((v1 - vT) * 0.125f) : 0.f;
      wb[j] = (unsigned)f2bf(e0) | ((unsigned)f2bf(e1) << 16);
    }
  }
  __syncthreads();

  // O_un = P_un[16x128] @ V[128x64]; den = P_un @ ones (extra MFMA column)
  f32x4 oacc[4] = {};
  f32x4 dacc = {};
  bf16x8 ones;
#pragma unroll
  for (int j = 0; j < 8; ++j) ones[j] = (__bf16)1.0f;
#pragma unroll
  for (int k0 = 0; k0 < 128; k0 += 32) {
    bf16x8 a = *(const bf16x8*)&Sc[(w * 16 + frow) * PP + k0 + fk8];
#pragma unroll
    for (int nt = 0; nt < 4; ++nt) {
      int e = nt * 16 + frow;
      bf16x8 bb = *(const bf16x8*)&Vt[e * PP + ((k0 + fk8) ^ (e & 56))];
      oacc[nt] = __builtin_amdgcn_mfma_f32_16x16x32_bf16(a, bb, oacc[nt], 0, 0, 0);
    }
    dacc = __builtin_amdgcn_mfma_f32_16x16x32_bf16(a, ones, dacc, 0, 0, 0);
  }
  float inv4[4];
#pragma unroll
  for (int r = 0; r < 4; ++r) inv4[r] = 1.f / dacc[r];
#pragma unroll
  for (int nt = 0; nt < 4; ++nt)
#pragma unroll
    for (int r = 0; r < 4; ++r)
      smil[(size_t)(b * 2048 + l0 + w * 16 + q * 4 + r) * 512 + h * 64 + nt * 16 + frow] =
          f2bf(oacc[nt][r] * inv4[r]);
}

// ---------------- fusion 2 scores: S2[bh][l 128][s 2048] bf16 ----------------
__global__ __launch_bounds__(256) void kf2scores(const unsigned short* __restrict__ Psmis,
                                                 const unsigned short* __restrict__ Pseqs,
                                                 unsigned short* __restrict__ S2) {
  __shared__ unsigned short As[128 * 32], Bs[128 * 32];
  int tid = threadIdx.x, lane = tid & 63, wave = tid >> 6;
  int st = blockIdx.x, bh = blockIdx.y;
  int b = bh >> 3, h = bh & 7;
  int s0 = st * 128;
  const unsigned short* Abase = Psmis + (size_t)b * 128 * NC + h * 64;
  const unsigned short* Bbase = Pseqs + (size_t)b * 2048 * NC + 512 + h * 64;
  f32x4 acc[4][4] = {};
  int wm = (wave >> 1) * 64, wn = (wave & 1) * 64;
  int frow = lane & 15, fk = (lane >> 4) * 8;
  for (int k0 = 0; k0 < 64; k0 += 32) {
    if (k0) __syncthreads();
#pragma unroll
    for (int j = 0; j < 2; ++j) {
      int ch = j * 256 + tid;
      int row = ch >> 2, kc = (ch & 3) * 8;
      gld16(Abase + (size_t)row * NC + k0 + kc, As + ch * 8);
      gld16(Bbase + (size_t)(s0 + row) * NC + k0 + kc, Bs + ch * 8);
    }
    __syncthreads();
    bf16x8 af[4], bfv[4];
#pragma unroll
    for (int mt = 0; mt < 4; ++mt) af[mt] = *(const bf16x8*)&As[(wm + mt * 16 + frow) * 32 + fk];
#pragma unroll
    for (int nt = 0; nt < 4; ++nt) bfv[nt] = *(const bf16x8*)&Bs[(wn + nt * 16 + frow) * 32 + fk];
#pragma unroll
    for (int mt = 0; mt < 4; ++mt)
#pragma unroll
      for (int nt = 0; nt < 4; ++nt)
        acc[mt][nt] = __builtin_amdgcn_mfma_f32_16x16x32_bf16(af[mt], bfv[nt], acc[mt][nt], 0, 0, 0);
  }
  int q = lane >> 4, c15 = lane & 15;
  unsigned short* outp = S2 + (size_t)bh * 128 * 2048;
#pragma unroll
  for (int mt = 0; mt < 4; ++mt)
#pragma unroll
    for (int nt = 0; nt < 4; ++nt)
#pragma unroll
      for (int r = 0; r < 4; ++r)
        outp[(size_t)(wm + mt * 16 + q * 4 + r) * 2048 + s0 + wn + nt * 16 + c15] = f2bf(acc[mt][nt][r]);
}

// ---------------- fusion 2 select: top-32 of 2048 per row via bit-plane radix select ----------------
__global__ __launch_bounds__(256) void kf2select(const unsigned short* __restrict__ S2,
                                                 const unsigned short* __restrict__ Pseqs,
                                                 float* __restrict__ seqs_out) {
  __shared__ float pS[4][32];
  __shared__ int   sS[4][32];
  int tid = threadIdx.x, lane = tid & 63, w = tid >> 6;
  int rid = blockIdx.x * 4 + w;
  int l = rid & 127, bh = rid >> 7;
  int h = bh & 7, b = bh >> 3;
  const unsigned short* rowp = S2 + (size_t)rid * 2048;

  unsigned B[16];
  const uint4* p4 = (const uint4*)(rowp + lane * 32);
#pragma unroll
  for (int i = 0; i < 4; ++i) {
    uint4 qv = p4[i];
    B[i * 4 + 0] = qv.x; B[i * 4 + 1] = qv.y; B[i * 4 + 2] = qv.z; B[i * 4 + 3] = qv.w;
  }
#pragma unroll
  for (int i = 0; i < 16; ++i) {
    unsigned s = (B[i] >> 15) & 0x00010001u;
    B[i] = B[i] ^ (s * 0x7FFFu) ^ 0x80008000u;
  }
  TRANSPOSE16(B)
  unsigned act = 0xFFFFFFFFu, gt = 0u, Tv = 0u;
  int rem = 32;
#pragma unroll
  for (int bit = 15; bit >= 0; --bit) {
    unsigned bm = B[15 - bit] & act;
    int c = __popc(bm);
#pragma unroll
    for (int d = 1; d < 64; d <<= 1) c += __shfl_xor(c, d);
    bool take = (c >= rem);
    unsigned actx = act ^ bm;
    act = take ? bm : actx;
    gt = take ? gt : (gt | bm);
    rem = take ? rem : (rem - c);
    Tv = take ? (Tv | (1u << bit)) : Tv;
  }
  unsigned hT = (Tv & 0x8000u) ? (Tv ^ 0x8000u) : (Tv ^ 0xFFFFu);
  float vT = bf2f((unsigned short)hT);

  gt = pos2elem(gt);
  act = pos2elem(act);

  int pc_tie = __popc(act);
  int inc = pc_tie;
#pragma unroll
  for (int d = 1; d < 64; d <<= 1) { int y = __shfl_up(inc, d); if (lane >= d) inc += y; }
  int tie_pre = inc - pc_tie;
  int budget = rem - tie_pre;
  budget = budget < 0 ? 0 : (budget > pc_tie ? pc_tie : budget);
  int total_lane = __popc(gt) + budget;
  int inc2 = total_lane;
#pragma unroll
  for (int d = 1; d < 64; d <<= 1) { int y = __shfl_up(inc2, d); if (lane >= d) inc2 += y; }
  int slot = inc2 - total_lane;

  float lsum = 0.f;
  unsigned m = gt;
  while (m) {
    int e = __builtin_ctz(m); m &= m - 1;
    int gidx = (lane << 5) + e;
    float v = bf2f(rowp[gidx]);
    float ev = __expf((v - vT) * 0.125f);
    pS[w][slot] = ev; sS[w][slot] = gidx; ++slot; lsum += ev;
  }
  m = act;
  for (int taken = 0; taken < budget; ++taken) {
    int e = __builtin_ctz(m); m &= m - 1;
    int gidx = (lane << 5) + e;
    float v = bf2f(rowp[gidx]);
    float ev = __expf((v - vT) * 0.125f);
    pS[w][slot] = ev; sS[w][slot] = gidx; ++slot; lsum += ev;
  }
  float den = lsum;
#pragma unroll
  for (int d = 1; d < 64; d <<= 1) den += __shfl_xor(den, d);

  float acc = 0.f;
  const unsigned short* Vb = Pseqs + (size_t)(b * 2048) * NC + 1024 + h * 64 + lane;
#pragma unroll 8
  for (int t = 0; t < 32; ++t) {
    float pv = pS[w][t];
    int s = sS[w][t];
    acc += pv * bf2f(Vb[(size_t)s * NC]);
  }
  seqs_out[(size_t)(b * 128 + l) * 512 + h * 64 + lane] = acc / den;
}

// ---------------- pooling ----------------
__device__ __forceinline__ float dot8(uint4 pk, const float* w) {
  float s = bf2f((unsigned short)(pk.x & 0xFFFFu)) * w[0] + bf2f((unsigned short)(pk.x >> 16)) * w[1];
  s += bf2f((unsigned short)(pk.y & 0xFFFFu)) * w[2] + bf2f((unsigned short)(pk.y >> 16)) * w[3];
  s += bf2f((unsigned short)(pk.z & 0xFFFFu)) * w[4] + bf2f((unsigned short)(pk.z >> 16)) * w[5];
  s += bf2f((unsigned short)(pk.w & 0xFFFFu)) * w[6] + bf2f((unsigned short)(pk.w >> 16)) * w[7];
  return s;
}

__global__ __launch_bounds__(256) void kpool1a(const unsigned short* __restrict__ x,
                                               const float* __restrict__ wp, const float* __restrict__ bp,
                                               float* __restrict__ logits) {
  int tid = threadIdx.x, lane = tid & 63, wave = tid >> 6;
  int r = blockIdx.x * 4 + wave;
  uint4 pk = *(const uint4*)(x + (size_t)r * 512 + lane * 8);
  float acc = dot8(pk, wp + lane * 8);
#pragma unroll
  for (int d = 1; d < 64; d <<= 1) acc += __shfl_xor(acc, d);
  if (lane == 0) logits[r] = acc + bp[0];
}

// grid 256: b = bi>>4, ls = (bi>>1)&7, colhalf = bi&1
__global__ __launch_bounds__(256) void kpool1b(const unsigned short* __restrict__ x,
                                               const float* __restrict__ logits,
                                               float* __restrict__ aout, float* __restrict__ pp) {
  __shared__ float red[256];
  __shared__ float aS[256];
  int t = threadIdx.x;
  int b = blockIdx.x >> 4, ls = (blockIdx.x >> 1) & 7, cj = blockIdx.x & 1;
  const float* lg = logits + b * 2048;
  float lm = -FLT_MAX;
  for (int j = t; j < 2048; j += 256) lm = fmaxf(lm, lg[j]);
  red[t] = lm; __syncthreads();
  for (int s = 128; s > 0; s >>= 1) { if (t < s) red[t] = fmaxf(red[t], red[t + s]); __syncthreads(); }
  float M = red[0]; __syncthreads();
  float sm = 0.f;
  for (int j = t; j < 2048; j += 256) sm += __expf(lg[j] - M);
  red[t] = sm; __syncthreads();
  for (int s = 128; s > 0; s >>= 1) { if (t < s) red[t] += red[t + s]; __syncthreads(); }
  float D = red[0];
  int l0 = ls * 256;
  float a = __expf(lg[l0 + t] - M) / D;
  aS[t] = a;
  if (cj == 0) aout[b * 2048 + l0 + t] = a;
  __syncthreads();
  int col = cj * 256 + t;
  float acc0 = 0.f;
  const unsigned short* xb = x + ((size_t)b * 2048 + l0) * 512 + col;
#pragma unroll 8
  for (int ll = 0; ll < 256; ++ll) acc0 += aS[ll] * bf2f(xb[(size_t)ll * 512]);
  pp[(size_t)(b * 8 + ls) * 512 + col] = acc0;
}

__global__ __launch_bounds__(256) void kpool2(const float* __restrict__ x,
                                              const float* __restrict__ wp, const float* __restrict__ bp,
                                              float* __restrict__ a2out, float* __restrict__ pooled2) {
  __shared__ float lgS[128];
  int t = threadIdx.x, lane = t & 63, wave = t >> 6;
  int b = blockIdx.x;
  for (int i = 0; i < 32; ++i) {
    int row = wave * 32 + i;
    const float* xp = x + (size_t)(b * 128 + row) * 512;
    float acc = 0.f;
#pragma unroll
    for (int j = 0; j < 8; ++j) acc += xp[lane + 64 * j] * wp[lane + 64 * j];
#pragma unroll
    for (int d = 1; d < 64; d <<= 1) acc += __shfl_xor(acc, d);
    if (lane == 0) lgS[row] = acc + bp[0];
  }
  __syncthreads();
  if (wave == 0) {
    float a0 = lgS[lane], a1 = lgS[64 + lane];
    float m = fmaxf(a0, a1);
#pragma unroll
    for (int d = 1; d < 64; d <<= 1) m = fmaxf(m, __shfl_xor(m, d));
    float e0 = __expf(a0 - m), e1 = __expf(a1 - m);
    float sden = e0 + e1;
#pragma unroll
    for (int d = 1; d < 64; d <<= 1) sden += __shfl_xor(sden, d);
    a0 = e0 / sden; a1 = e1 / sden;
    lgS[lane] = a0; lgS[64 + lane] = a1;
    a2out[b * 128 + lane] = a0;
    a2out[b * 128 + 64 + lane] = a1;
  }
  __syncthreads();
  float acc0 = 0.f, acc1 = 0.f;
#pragma unroll 4
  for (int row = 0; row < 128; ++row) {
    float av = lgS[row];
    const float* xp = x + (size_t)(b * 128 + row) * 512;
    acc0 += av * xp[t];
    acc1 += av * xp[t + 256];
  }
  pooled2[(size_t)b * 512 + t] = acc0;
  pooled2[(size_t)b * 512 + t + 256] = acc1;
}

// ---------------- head ----------------
__global__ __launch_bounds__(256) void kemb(const float* __restrict__ pp, const float* __restrict__ pooled2,
                                            float* __restrict__ embo, float* __restrict__ embws) {
  __shared__ float red[256];
  int t = threadIdx.x, b = blockIdx.x;
  float pre[4];
#pragma unroll
  for (int qq = 0; qq < 4; ++qq) {
    int c = qq * 256 + t;
    float s;
    if (c < 512) {
      s = 0.f;
      for (int lsl = 0; lsl < 8; ++lsl) s += pp[(size_t)(b * 8 + lsl) * 512 + c];
    } else {
      s = pooled2[(size_t)b * 512 + (c - 512)];
    }
    pre[qq] = s;
  }
  float ssq = pre[0] * pre[0] + pre[1] * pre[1] + pre[2] * pre[2] + pre[3] * pre[3];
  red[t] = ssq; __syncthreads();
  for (int s2 = 128; s2 > 0; s2 >>= 1) { if (t < s2) red[t] += red[t + s2]; __syncthreads(); }
  float inv = 1.f / fmaxf(sqrtf(red[0]), 1e-12f);
#pragma unroll
  for (int qq = 0; qq < 4; ++qq) {
    int c = qq * 256 + t;
    float e = pre[qq] * inv;
    embo[(size_t)b * 1024 + c] = e;
    embws[(size_t)b * 1024 + c] = e;
  }
}

__global__ __launch_bounds__(256) void kmlp(const float* __restrict__ in, const float* __restrict__ W,
                                            const float* __restrict__ bias, float* __restrict__ out,
                                            int IN, int ON) {
  __shared__ float e[1024];
  int t = threadIdx.x;
  int chunks = ON >> 8;
  int b = blockIdx.x / chunks, jc = blockIdx.x % chunks;
  for (int q = t; q < IN; q += 256) e[q] = in[(size_t)b * IN + q];
  __syncthreads();
  int j = jc * 256 + t;
  float acc = bias[j];
#pragma unroll 8
  for (int i = 0; i < IN; ++i) acc += e[i] * W[(size_t)i * ON + j];
  out[(size_t)b * ON + j] = fmaxf(acc, 0.f);
}

__global__ void kout(const float* __restrict__ h2, const float* __restrict__ W3, const float* __restrict__ b3,
                     float* __restrict__ outp) {
  int b = blockIdx.x, lane = threadIdx.x;
  float acc = 0.f;
#pragma unroll
  for (int j = 0; j < 8; ++j) acc += h2[(size_t)b * 512 + lane + 64 * j] * W3[lane + 64 * j];
#pragma unroll
  for (int d = 1; d < 64; d <<= 1) acc += __shfl_xor(acc, d);
  if (lane == 0) outp[b] = acc + b3[0];
}

// ---------------- launch ----------------
extern "C" void kernel_launch(void* const* d_in, const int* in_sizes, int n_in,
                              void* d_out, int out_size, void* d_ws, size_t ws_size,
                              hipStream_t stream) {
  const float* seqs = (const float*)d_in[0];
  const float* smis = (const float*)d_in[1];
  const float* Wq = (const float*)d_in[2];
  const float* bq = (const float*)d_in[3];
  const float* Wk = (const float*)d_in[4];
  const float* bk = (const float*)d_in[5];
  const float* Wv = (const float*)d_in[6];
  const float* bv = (const float*)d_in[7];
  const float* wp = (const float*)d_in[8];
  const float* bp = (const float*)d_in[9];
  const float* W1 = (const float*)d_in[10];
  const float* b1 = (const float*)d_in[11];
  const float* W2 = (const float*)d_in[12];
  const float* b2 = (const float*)d_in[13];
  const float* W3 = (const float*)d_in[14];
  const float* b3 = (const float*)d_in[15];
  float* out = (float*)d_out;
  char* ws = (char*)d_ws;

  float* nrm_s = (float*)(ws + WS_NRM_S);
  float* nrm_m = (float*)(ws + WS_NRM_M);
  float* part_s = (float*)(ws + WS_PART);
  float* part_m = (float*)(ws + WS_PARTM);
  float* bcat = (float*)(ws + WS_BCAT);
  float* log1 = (float*)(ws + WS_LOG1);
  float* pp1 = (float*)(ws + WS_PP1);
  float* pooled2 = (float*)(ws + WS_POOL2);
  float* embws = (float*)(ws + WS_EMB);
  float* h1 = (float*)(ws + WS_H1);
  float* h2 = (float*)(ws + WS_H2);
  unsigned short* wct = (unsigned short*)(ws + WS_WCT);
  unsigned short* smis_nb = (unsigned short*)(ws + WS_SMISNB);
  unsigned short* Psmis = (unsigned short*)(ws + WS_PSMIS);
  float* seqs_out = (float*)(ws + WS_SEQSOUT);
  unsigned short* seqs_nb = (unsigned short*)(ws + WS_SEQSNB);
  unsigned short* Pseqs = (unsigned short*)(ws + WS_PSEQS);
  unsigned short* smil = (unsigned short*)(ws + WS_SMILOUT);
  unsigned short* S2 = (unsigned short*)(ws + WS_S2);

  // 1. column norms (part buffers alias Pseqs region; consumed before kgemm writes it)
  knorm_part<<<dim3(64, 16), 128, 0, stream>>>(seqs, part_s, 32, 64);
  knorm_part<<<dim3(4, 16), 128, 0, stream>>>(smis, part_m, 32, 4);
  knorm_fin<<<dim3(32), 256, 0, stream>>>(part_s, nrm_s, 64);
  knorm_fin<<<dim3(32), 256, 0, stream>>>(part_m, nrm_m, 4);
  // 2. normalize + cast to bf16
  kcast<<<dim3(16384), 256, 0, stream>>>(seqs, nrm_s, seqs_nb, 20, 16 * 2048 * 512);
  kcast<<<dim3(1024), 256, 0, stream>>>(smis, nrm_m, smis_nb, 16, 16 * 128 * 512);
  // 3. weight prep
  kprepw<<<dim3(16, 16, 3), 256, 0, stream>>>(Wq, Wk, Wv, wct);
  kprepb<<<dim3(6), 256, 0, stream>>>(bq, bk, bv, bcat);
  // 4. fused QKV projections (1D grid, in-kernel XCD remap, LDS dbuf)
  kgemm<<<dim3(3072), 256, 0, stream>>>(seqs_nb, wct, bcat, Pseqs, 512, NC, 12);
  kgemm<<<dim3(192), 256, 0, stream>>>(smis_nb, wct, bcat, Psmis, 512, NC, 12);
  // 5. fusion 1 attention (writes smil, aliases dead seqs_nb)
  kfusion1<<<dim3(32, 8, 16), 256, 0, stream>>>(Pseqs, Psmis, smil);
  // 6. pool 1
  kpool1a<<<dim3(8192), 256, 0, stream>>>(smil, wp, bp, log1);
  kpool1b<<<dim3(256), 256, 0, stream>>>(smil, log1, out + OUT_A1, pp1);
  // 7. fusion 2
  kf2scores<<<dim3(16, 128), 256, 0, stream>>>(Psmis, Pseqs, S2);
  kf2select<<<dim3(4096), 256, 0, stream>>>(S2, Pseqs, seqs_out);
  kpool2<<<dim3(16), 256, 0, stream>>>(seqs_out, wp, bp, out + OUT_A2, pooled2);
  // 8. head
  kemb<<<dim3(16), 256, 0, stream>>>(pp1, pooled2, out + OUT_EMB, embws);
  kmlp<<<dim3(64), 256, 0, stream>>>(embws, W1, b1, h1, 1024, 1024);
  kmlp<<<dim3(32), 256, 0, stream>>>(h1, W2, b2, h2, 1024, 512);
  kout<<<dim3(16), 64, 0, stream>>>(h2, W3, b3, out + OUT_OUT);
}

// Round 12
// 528.628 us; speedup vs baseline: 1.1635x; 1.0726x over previous
//
#include <hip/hip_runtime.h>
#include <cfloat>
#include <cstdint>

// ---------------- problem constants ----------------
#define NC 1536   // 3*H concatenated projection width

// d_out float offsets: emb[16,1024] | out[16] | smiles_attn_pool[16,2048] | seqs_attn_pool[16,128]
#define OUT_EMB 0
#define OUT_OUT 16384
#define OUT_A1  16400
#define OUT_A2  49168

// ws byte offsets
#define WS_NRM_S   0u
#define WS_NRM_M   32768u
#define WS_BCAT    360448u
#define WS_LOG1    366592u
#define WS_PP1     505856u
#define WS_EMB     800768u
#define WS_H1      866304u
#define WS_WCT     1048576u
#define WS_SMISNB  2621440u
#define WS_PSMIS   4718592u
#define WS_SEQSOUT 11010048u
#define WS_SEQSNB  15204352u
#define WS_PSEQS   48758784u
#define WS_SMILOUT WS_SEQSNB          // seqs_nb dead after GEMM1; reuse for smiles_out
#define WS_S2      149422080u          // ws total need ~216.5 MB
// norm partials are consumed before Pseqs is written -> alias that region
#define WS_PART    WS_PSEQS
#define WS_PARTM   (WS_PSEQS + 2097152u)

typedef float f32x4 __attribute__((ext_vector_type(4)));
typedef __bf16 bf16x8 __attribute__((ext_vector_type(8)));
typedef unsigned short u16x8 __attribute__((ext_vector_type(8)));

__device__ __forceinline__ float bf2f(unsigned short h) {
  return __uint_as_float(((unsigned int)h) << 16);
}
__device__ __forceinline__ unsigned short f2bf(float f) {
  unsigned int u = __float_as_uint(f);
  return (unsigned short)((u + 0x7FFFu + ((u >> 16) & 1u)) >> 16);
}
__device__ __forceinline__ void gld16(const unsigned short* g, unsigned short* l) {
  __builtin_amdgcn_global_load_lds(
      (__attribute__((address_space(1))) unsigned int*)(uintptr_t)g,
      (__attribute__((address_space(3))) unsigned int*)l, 16, 0, 0);
}

// position-space mask -> element-space mask for the anti-diagonal transpose layout:
// element 2c sits at position 15-c (low half), element 2c+1 at position 31-c (high half)
__device__ __forceinline__ unsigned pos2elem(unsigned m) {
  unsigned lo = __brev(m & 0xFFFFu) >> 16;   // bit i = m bit (15-i)
  unsigned hi = __brev(m >> 16) >> 16;       // bit i = m bit (31-i)
  lo = (lo | (lo << 8)) & 0x00FF00FFu;
  lo = (lo | (lo << 4)) & 0x0F0F0F0Fu;
  lo = (lo | (lo << 2)) & 0x33333333u;
  lo = (lo | (lo << 1)) & 0x55555555u;
  hi = (hi | (hi << 8)) & 0x00FF00FFu;
  hi = (hi | (hi << 4)) & 0x0F0F0F0Fu;
  hi = (hi | (hi << 2)) & 0x33333333u;
  hi = (hi | (hi << 1)) & 0x55555555u;
  return lo | (hi << 1);
}

#define TRANSPOSE16(B)                                                                             \
  {                                                                                                \
    unsigned t;                                                                                    \
    t = (B[0] ^ (B[8] >> 8)) & 0x00FF00FFu; B[0] ^= t; B[8] ^= (t << 8);                           \
    t = (B[1] ^ (B[9] >> 8)) & 0x00FF00FFu; B[1] ^= t; B[9] ^= (t << 8);                           \
    t = (B[2] ^ (B[10] >> 8)) & 0x00FF00FFu; B[2] ^= t; B[10] ^= (t << 8);                         \
    t = (B[3] ^ (B[11] >> 8)) & 0x00FF00FFu; B[3] ^= t; B[11] ^= (t << 8);                         \
    t = (B[4] ^ (B[12] >> 8)) & 0x00FF00FFu; B[4] ^= t; B[12] ^= (t << 8);                         \
    t = (B[5] ^ (B[13] >> 8)) & 0x00FF00FFu; B[5] ^= t; B[13] ^= (t << 8);                         \
    t = (B[6] ^ (B[14] >> 8)) & 0x00FF00FFu; B[6] ^= t; B[14] ^= (t << 8);                         \
    t = (B[7] ^ (B[15] >> 8)) & 0x00FF00FFu; B[7] ^= t; B[15] ^= (t << 8);                         \
    t = (B[0] ^ (B[4] >> 4)) & 0x0F0F0F0Fu; B[0] ^= t; B[4] ^= (t << 4);                           \
    t = (B[1] ^ (B[5] >> 4)) & 0x0F0F0F0Fu; B[1] ^= t; B[5] ^= (t << 4);                           \
    t = (B[2] ^ (B[6] >> 4)) & 0x0F0F0F0Fu; B[2] ^= t; B[6] ^= (t << 4);                           \
    t = (B[3] ^ (B[7] >> 4)) & 0x0F0F0F0Fu; B[3] ^= t; B[7] ^= (t << 4);                           \
    t = (B[8] ^ (B[12] >> 4)) & 0x0F0F0F0Fu; B[8] ^= t; B[12] ^= (t << 4);                         \
    t = (B[9] ^ (B[13] >> 4)) & 0x0F0F0F0Fu; B[9] ^= t; B[13] ^= (t << 4);                         \
    t = (B[10] ^ (B[14] >> 4)) & 0x0F0F0F0Fu; B[10] ^= t; B[14] ^= (t << 4);                       \
    t = (B[11] ^ (B[15] >> 4)) & 0x0F0F0F0Fu; B[11] ^= t; B[15] ^= (t << 4);                       \
    t = (B[0] ^ (B[2] >> 2)) & 0x33333333u; B[0] ^= t; B[2] ^= (t << 2);                           \
    t = (B[1] ^ (B[3] >> 2)) & 0x33333333u; B[1] ^= t; B[3] ^= (t << 2);                           \
    t = (B[4] ^ (B[6] >> 2)) & 0x33333333u; B[4] ^= t; B[6] ^= (t << 2);                           \
    t = (B[5] ^ (B[7] >> 2)) & 0x33333333u; B[5] ^= t; B[7] ^= (t << 2);                           \
    t = (B[8] ^ (B[10] >> 2)) & 0x33333333u; B[8] ^= t; B[10] ^= (t << 2);                         \
    t = (B[9] ^ (B[11] >> 2)) & 0x33333333u; B[9] ^= t; B[11] ^= (t << 2);                         \
    t = (B[12] ^ (B[14] >> 2)) & 0x33333333u; B[12] ^= t; B[14] ^= (t << 2);                       \
    t = (B[13] ^ (B[15] >> 2)) & 0x33333333u; B[13] ^= t; B[15] ^= (t << 2);                       \
    t = (B[0] ^ (B[1] >> 1)) & 0x55555555u; B[0] ^= t; B[1] ^= (t << 1);                           \
    t = (B[2] ^ (B[3] >> 1)) & 0x55555555u; B[2] ^= t; B[3] ^= (t << 1);                           \
    t = (B[4] ^ (B[5] >> 1)) & 0x55555555u; B[4] ^= t; B[5] ^= (t << 1);                           \
    t = (B[6] ^ (B[7] >> 1)) & 0x55555555u; B[6] ^= t; B[7] ^= (t << 1);                           \
    t = (B[8] ^ (B[9] >> 1)) & 0x55555555u; B[8] ^= t; B[9] ^= (t << 1);                           \
    t = (B[10] ^ (B[11] >> 1)) & 0x55555555u; B[10] ^= t; B[11] ^= (t << 1);                       \
    t = (B[12] ^ (B[13] >> 1)) & 0x55555555u; B[12] ^= t; B[13] ^= (t << 1);                       \
    t = (B[14] ^ (B[15] >> 1)) & 0x55555555u; B[14] ^= t; B[15] ^= (t << 1);                       \
  }

// ---------------- column-wise l2 norms (axis=1), both inputs in one launch ----------------
__global__ __launch_bounds__(128) void knorm_part(const float* __restrict__ seqs, const float* __restrict__ smis,
                                                  float* __restrict__ part_s, float* __restrict__ part_m) {
  int ls = blockIdx.x, b = blockIdx.y, t = threadIdx.x;
  const float* x; float* part; int slab;
  if (ls < 64) { x = seqs; part = part_s + (size_t)(b * 64 + ls) * 512; slab = b * 64 + ls; }
  else { x = smis; part = part_m + (size_t)(b * 4 + (ls - 64)) * 512; slab = b * 4 + (ls - 64); }
  const float* xp = x + (size_t)slab * 32 * 512 + t * 4;
  float ax = 0.f, ay = 0.f, az = 0.f, aw = 0.f;
  for (int l = 0; l < 32; ++l) {
    float4 v = *(const float4*)(xp + (size_t)l * 512);
    ax += v.x * v.x; ay += v.y * v.y; az += v.z * v.z; aw += v.w * v.w;
  }
  float4 r = {ax, ay, az, aw};
  *(float4*)(part + t * 4) = r;
}

// grid 64: bh<32 seqs (NS=64), else smis (NS=4)
__global__ __launch_bounds__(256) void knorm_fin(const float* __restrict__ part_s, const float* __restrict__ part_m,
                                                 float* __restrict__ nrm_s, float* __restrict__ nrm_m) {
  int bh0 = blockIdx.x, t = threadIdx.x;
  const float* part; float* inv; int NS, bh;
  if (bh0 < 32) { part = part_s; inv = nrm_s; NS = 64; bh = bh0; }
  else { part = part_m; inv = nrm_m; NS = 4; bh = bh0 - 32; }
  int b = bh >> 1, col = (bh & 1) * 256 + t;
  float s = 0.f;
  for (int j = 0; j < NS; ++j) s += part[((size_t)(b * NS + j)) * 512 + col];
  inv[(size_t)b * 512 + col] = 1.f / fmaxf(sqrtf(s), 1e-12f);
}

// both casts in one launch: blocks [0,16384) seqs, [16384,17408) smis
__global__ __launch_bounds__(256) void kcast(const float* __restrict__ seqs, const float* __restrict__ smis,
                                             const float* __restrict__ nrm_s, const float* __restrict__ nrm_m,
                                             unsigned short* __restrict__ seqs_nb, unsigned short* __restrict__ smis_nb) {
  const float* x; const float* inv; unsigned short* o; int i4, shiftB;
  if (blockIdx.x < 16384) {
    i4 = (blockIdx.x * 256 + threadIdx.x) * 4; x = seqs; inv = nrm_s; o = seqs_nb; shiftB = 20;
  } else {
    i4 = ((blockIdx.x - 16384) * 256 + threadIdx.x) * 4; x = smis; inv = nrm_m; o = smis_nb; shiftB = 16;
  }
  int b = i4 >> shiftB;
  float4 v = *(const float4*)(x + i4);
  float4 nv = *(const float4*)(inv + (b << 9) + (i4 & 511));
  ushort4 r;
  r.x = f2bf(v.x * nv.x); r.y = f2bf(v.y * nv.y);
  r.z = f2bf(v.z * nv.z); r.w = f2bf(v.w * nv.w);
  *(ushort4*)(o + i4) = r;
}

// ---------------- weight prep: WcatT[1536][512] bf16 (B^T layout), bcat, zero log1 ----------------
__global__ __launch_bounds__(256) void kprepw(const float* __restrict__ Wq, const float* __restrict__ Wk,
                                              const float* __restrict__ Wv, unsigned short* __restrict__ WT) {
  __shared__ float T[32][33];
  int ti = blockIdx.x, tj = blockIdx.y, m = blockIdx.z;
  const float* W = m == 0 ? Wq : (m == 1 ? Wk : Wv);
  int c = threadIdx.x & 31, r0 = threadIdx.x >> 5;
#pragma unroll
  for (int j = 0; j < 4; ++j) {
    int r = r0 + j * 8;
    T[r][c] = W[(size_t)(ti * 32 + r) * 512 + tj * 32 + c];
  }
  __syncthreads();
#pragma unroll
  for (int j = 0; j < 4; ++j) {
    int r = r0 + j * 8;
    WT[(size_t)(m * 512 + tj * 32 + r) * 512 + ti * 32 + c] = f2bf(T[c][r]);
  }
}

// bcat (1536) + zero log1 (32768)
__global__ void kprepbz(const float* bq, const float* bk, const float* bv, float* bcat, float* log1) {
  int i = blockIdx.x * 256 + threadIdx.x;
  if (i < 1536) bcat[i] = i < 512 ? bq[i] : (i < 1024 ? bk[i - 512] : bv[i - 1024]);
  else if (i < 1536 + 32768) log1[i - 1536] = 0.f;
}

// ---------------- bf16 MFMA GEMM: C[M,N] = A[M,K] @ Bt[N,K]^T + bias ----------------
// v3 + merged big/small dispatch. LDS dbuf (1 barrier/K-iter) + XCD remap.
// R10 lesson: register-level global B prefetch regresses (__syncthreads drains vmcnt(0)).
__global__ __launch_bounds__(256) void kgemm(const unsigned short* __restrict__ A1,
                                             const unsigned short* __restrict__ A2,
                                             const unsigned short* __restrict__ Bt,
                                             const float* __restrict__ bias,
                                             unsigned short* __restrict__ C1,
                                             unsigned short* __restrict__ C2) {
  const int K = 512, N = NC, NT = 12;
  __shared__ unsigned short As[2][128 * 32], Bs[2][128 * 32];
  int tid = threadIdx.x, lane = tid & 63, wave = tid >> 6;
  int id = blockIdx.x;
  const unsigned short* A; unsigned short* C;
  if (id < 3072) { A = A1; C = C1; }
  else { A = A2; C = C2; id -= 3072; }
  int xcd = id & 7, j = id >> 3;
  int mloc = j / NT, n = j - mloc * NT;
  int m0 = (mloc * 8 + xcd) * 128, n0 = n * 128;
  f32x4 acc[4][4] = {};
  int wm = (wave >> 1) * 64, wn = (wave & 1) * 64;
  int frow = lane & 15, fk = (lane >> 4) * 8;

  auto stage = [&](int buf, int k0) {
#pragma unroll
    for (int jj = 0; jj < 2; ++jj) {
      int ch = jj * 256 + tid;
      int row = ch >> 2, kc = (ch & 3) * 8;
      gld16(A + (size_t)(m0 + row) * K + k0 + kc, As[buf] + ch * 8);
      gld16(Bt + (size_t)(n0 + row) * K + k0 + kc, Bs[buf] + ch * 8);
    }
  };

  stage(0, 0);
  __syncthreads();
  int nk = K >> 5;
  for (int it = 0; it < nk; ++it) {
    int cur = it & 1;
    if (it + 1 < nk) stage(cur ^ 1, (it + 1) << 5);
    bf16x8 af[4], bfv[4];
#pragma unroll
    for (int mt = 0; mt < 4; ++mt) af[mt] = *(const bf16x8*)&As[cur][(wm + mt * 16 + frow) * 32 + fk];
#pragma unroll
    for (int nt = 0; nt < 4; ++nt) bfv[nt] = *(const bf16x8*)&Bs[cur][(wn + nt * 16 + frow) * 32 + fk];
#pragma unroll
    for (int mt = 0; mt < 4; ++mt)
#pragma unroll
      for (int nt = 0; nt < 4; ++nt)
        acc[mt][nt] = __builtin_amdgcn_mfma_f32_16x16x32_bf16(af[mt], bfv[nt], acc[mt][nt], 0, 0, 0);
    __syncthreads();
  }
  int q = lane >> 4, c15 = lane & 15;
#pragma unroll
  for (int mt = 0; mt < 4; ++mt)
#pragma unroll
    for (int nt = 0; nt < 4; ++nt) {
      int col = n0 + wn + nt * 16 + c15;
      float bv = bias[col];
#pragma unroll
      for (int r = 0; r < 4; ++r) {
        int row = m0 + wm + mt * 16 + q * 4 + r;
        C[(size_t)row * N + col] = f2bf(acc[mt][nt][r] + bv);
      }
    }
}

// ---------------- fusion 1: Q=seqs(2048) K,V=smis(128); top-32 of 128 ----------------
// v5: v4 + fused pool-1 logits (O . w_pool partials via atomicAdd; bias dropped,
// softmax shift-invariant) -> kpool1a eliminated.
__global__ __launch_bounds__(256) void kfusion1(const unsigned short* __restrict__ Pseqs,
                                                const unsigned short* __restrict__ Psmis,
                                                const float* __restrict__ wp,
                                                unsigned short* __restrict__ smil,
                                                float* __restrict__ logits) {
  constexpr int PP = 136;                 // halfword pitch, rows 16B-aligned
  __shared__ unsigned short Sc[64 * PP];  // scores, then unnormalized P (bf16)
  __shared__ unsigned short Vt[64 * PP];  // V^T [e][s ^ (e&56)] (swizzled)
  int tid = threadIdx.x, lane = tid & 63, w = tid >> 6;
  int lt = blockIdx.x, h = blockIdx.y, b = blockIdx.z;
  int l0 = lt * 64;
  int frow = lane & 15, q = lane >> 4, fk8 = q * 8;

  // stage V^T, XOR swizzle on s-blocks
  for (int ch = tid; ch < 1024; ch += 256) {
    int s = ch >> 3, e8 = (ch & 7) * 8;
    u16x8 vv = *(const u16x8*)&Psmis[(size_t)(b * 128 + s) * NC + 1024 + h * 64 + e8];
#pragma unroll
    for (int j = 0; j < 8; ++j) {
      int e = e8 + j;
      Vt[e * PP + (s ^ (e & 56))] = vv[j];
    }
  }

  // scores: wave w's 16 Q-rows x 128 keys, fragments from global (L2-hot)
  {
    f32x4 acc[8] = {};
    const unsigned short* qrow = Pseqs + (size_t)(b * 2048 + l0 + w * 16 + frow) * NC + h * 64 + fk8;
#pragma unroll
    for (int ks = 0; ks < 2; ++ks) {
      bf16x8 a = *(const bf16x8*)(qrow + ks * 32);
#pragma unroll
      for (int nt = 0; nt < 8; ++nt) {
        bf16x8 bb = *(const bf16x8*)&Psmis[(size_t)(b * 128 + nt * 16 + frow) * NC + 512 + h * 64 + ks * 32 + fk8];
        acc[nt] = __builtin_amdgcn_mfma_f32_16x16x32_bf16(a, bb, acc[nt], 0, 0, 0);
      }
    }
#pragma unroll
    for (int nt = 0; nt < 8; ++nt)
#pragma unroll
      for (int r = 0; r < 4; ++r)
        Sc[(w * 16 + q * 4 + r) * PP + nt * 16 + frow] = f2bf(acc[nt][r]);
  }
  __syncthreads();

  // selection: lane owns 32 cols (seg = lane&3) of row (lane>>2); 16 rows per wave in one pass
  {
    int i = lane >> 2, seg = lane & 3;
    int row = w * 16 + i;
    unsigned short* rb = &Sc[row * PP + seg * 32];
    unsigned orig[16], B[16];
#pragma unroll
    for (int jb = 0; jb < 4; ++jb) {
      uint4 qv = *(const uint4*)(rb + jb * 8);
      orig[jb * 4 + 0] = qv.x; orig[jb * 4 + 1] = qv.y;
      orig[jb * 4 + 2] = qv.z; orig[jb * 4 + 3] = qv.w;
    }
#pragma unroll
    for (int j = 0; j < 16; ++j) {
      unsigned s = (orig[j] >> 15) & 0x00010001u;
      B[j] = orig[j] ^ (s * 0x7FFFu) ^ 0x80008000u;
    }
    TRANSPOSE16(B)
    unsigned act = 0xFFFFFFFFu, gt = 0u, Tv = 0u;
    int rem = 32;
#pragma unroll
    for (int bit = 15; bit >= 0; --bit) {
      unsigned bm = B[15 - bit] & act;
      int c = __popc(bm);
      c += __shfl_xor(c, 1);
      c += __shfl_xor(c, 2);
      bool take = (c >= rem);
      act = take ? bm : (act ^ bm);
      gt = take ? gt : (gt | bm);
      rem = take ? rem : (rem - c);
      Tv = take ? (Tv | (1u << bit)) : Tv;
    }
    unsigned hT = (Tv & 0x8000u) ? (Tv ^ 0x8000u) : (Tv ^ 0xFFFFu);
    float vT = bf2f((unsigned short)hT);
    unsigned gtE = pos2elem(gt), actE = pos2elem(act);
    int pc = __popc(actE);
    int pr1 = __shfl_up(pc, 1);
    int inc = pc + ((seg >= 1) ? pr1 : 0);
    int pr2 = __shfl_up(inc, 2);
    inc += ((seg >= 2) ? pr2 : 0);
    int tie_pre = inc - pc;
    int budget = rem - tie_pre;
    budget = budget < 0 ? 0 : (budget > pc ? pc : budget);
    unsigned selT = 0u, m = actE;
    for (int t = 0; t < budget; ++t) { unsigned bb2 = m & (~m + 1u); selT |= bb2; m ^= bb2; }
    unsigned sel = gtE | selT;
    unsigned* wb = (unsigned*)rb;
#pragma unroll
    for (int j = 0; j < 16; ++j) {
      unsigned d = orig[j];
      float v0 = bf2f((unsigned short)(d & 0xFFFFu));
      float v1 = bf2f((unsigned short)(d >> 16));
      float e0 = ((sel >> (2 * j)) & 1u) ? __expf((v0 - vT) * 0.125f) : 0.f;
      float e1 = ((sel >> (2 * j + 1)) & 1u) ? __expf((v1 - vT) * 0.125f) : 0.f;
      wb[j] = (unsigned)f2bf(e0) | ((unsigned)f2bf(e1) << 16);
    }
  }
  __syncthreads();

  // O_un = P_un[16x128] @ V[128x64]; den = P_un @ ones (extra MFMA column)
  f32x4 oacc[4] = {};
  f32x4 dacc = {};
  bf16x8 ones;
#pragma unroll
  for (int j = 0; j < 8; ++j) ones[j] = (__bf16)1.0f;
#pragma unroll
  for (int k0 = 0; k0 < 128; k0 += 32) {
    bf16x8 a = *(const bf16x8*)&Sc[(w * 16 + frow) * PP + k0 + fk8];
#pragma unroll
    for (int nt = 0; nt < 4; ++nt) {
      int e = nt * 16 + frow;
      bf16x8 bb = *(const bf16x8*)&Vt[e * PP + ((k0 + fk8) ^ (e & 56))];
      oacc[nt] = __builtin_amdgcn_mfma_f32_16x16x32_bf16(a, bb, oacc[nt], 0, 0, 0);
    }
    dacc = __builtin_amdgcn_mfma_f32_16x16x32_bf16(a, ones, dacc, 0, 0, 0);
  }
  float inv4[4];
#pragma unroll
  for (int r = 0; r < 4; ++r) inv4[r] = 1.f / dacc[r];
  // write O and accumulate pool-1 logit partials
  float wv[4];
#pragma unroll
  for (int nt = 0; nt < 4; ++nt) wv[nt] = wp[h * 64 + nt * 16 + frow];
  float lg[4];
#pragma unroll
  for (int r = 0; r < 4; ++r) lg[r] = 0.f;
#pragma unroll
  for (int nt = 0; nt < 4; ++nt)
#pragma unroll
    for (int r = 0; r < 4; ++r) {
      float ov = oacc[nt][r] * inv4[r];
      smil[(size_t)(b * 2048 + l0 + w * 16 + q * 4 + r) * 512 + h * 64 + nt * 16 + frow] = f2bf(ov);
      lg[r] += ov * wv[nt];
    }
#pragma unroll
  for (int d = 1; d < 16; d <<= 1)
#pragma unroll
    for (int r = 0; r < 4; ++r) lg[r] += __shfl_xor(lg[r], d);
  if (frow == 0) {
#pragma unroll
    for (int r = 0; r < 4; ++r)
      atomicAdd(&logits[b * 2048 + l0 + w * 16 + q * 4 + r], lg[r]);
  }
}

// ---------------- fusion 2 scores: S2[bh][l 128][s 2048] bf16 ----------------
__global__ __launch_bounds__(256) void kf2scores(const unsigned short* __restrict__ Psmis,
                                                 const unsigned short* __restrict__ Pseqs,
                                                 unsigned short* __restrict__ S2) {
  __shared__ unsigned short As[128 * 32], Bs[128 * 32];
  int tid = threadIdx.x, lane = tid & 63, wave = tid >> 6;
  int st = blockIdx.x, bh = blockIdx.y;
  int b = bh >> 3, h = bh & 7;
  int s0 = st * 128;
  const unsigned short* Abase = Psmis + (size_t)b * 128 * NC + h * 64;
  const unsigned short* Bbase = Pseqs + (size_t)b * 2048 * NC + 512 + h * 64;
  f32x4 acc[4][4] = {};
  int wm = (wave >> 1) * 64, wn = (wave & 1) * 64;
  int frow = lane & 15, fk = (lane >> 4) * 8;
  for (int k0 = 0; k0 < 64; k0 += 32) {
    if (k0) __syncthreads();
#pragma unroll
    for (int j = 0; j < 2; ++j) {
      int ch = j * 256 + tid;
      int row = ch >> 2, kc = (ch & 3) * 8;
      gld16(Abase + (size_t)row * NC + k0 + kc, As + ch * 8);
      gld16(Bbase + (size_t)(s0 + row) * NC + k0 + kc, Bs + ch * 8);
    }
    __syncthreads();
    bf16x8 af[4], bfv[4];
#pragma unroll
    for (int mt = 0; mt < 4; ++mt) af[mt] = *(const bf16x8*)&As[(wm + mt * 16 + frow) * 32 + fk];
#pragma unroll
    for (int nt = 0; nt < 4; ++nt) bfv[nt] = *(const bf16x8*)&Bs[(wn + nt * 16 + frow) * 32 + fk];
#pragma unroll
    for (int mt = 0; mt < 4; ++mt)
#pragma unroll
      for (int nt = 0; nt < 4; ++nt)
        acc[mt][nt] = __builtin_amdgcn_mfma_f32_16x16x32_bf16(af[mt], bfv[nt], acc[mt][nt], 0, 0, 0);
  }
  int q = lane >> 4, c15 = lane & 15;
  unsigned short* outp = S2 + (size_t)bh * 128 * 2048;
#pragma unroll
  for (int mt = 0; mt < 4; ++mt)
#pragma unroll
    for (int nt = 0; nt < 4; ++nt)
#pragma unroll
      for (int r = 0; r < 4; ++r)
        outp[(size_t)(wm + mt * 16 + q * 4 + r) * 2048 + s0 + wn + nt * 16 + c15] = f2bf(acc[mt][nt][r]);
}

// ---------------- fusion 2 select: top-32 of 2048 per row via bit-plane radix select ----------------
__global__ __launch_bounds__(256) void kf2select(const unsigned short* __restrict__ S2,
                                                 const unsigned short* __restrict__ Pseqs,
                                                 float* __restrict__ seqs_out) {
  __shared__ float pS[4][32];
  __shared__ int   sS[4][32];
  int tid = threadIdx.x, lane = tid & 63, w = tid >> 6;
  int rid = blockIdx.x * 4 + w;
  int l = rid & 127, bh = rid >> 7;
  int h = bh & 7, b = bh >> 3;
  const unsigned short* rowp = S2 + (size_t)rid * 2048;

  unsigned B[16];
  const uint4* p4 = (const uint4*)(rowp + lane * 32);
#pragma unroll
  for (int i = 0; i < 4; ++i) {
    uint4 qv = p4[i];
    B[i * 4 + 0] = qv.x; B[i * 4 + 1] = qv.y; B[i * 4 + 2] = qv.z; B[i * 4 + 3] = qv.w;
  }
#pragma unroll
  for (int i = 0; i < 16; ++i) {
    unsigned s = (B[i] >> 15) & 0x00010001u;
    B[i] = B[i] ^ (s * 0x7FFFu) ^ 0x80008000u;
  }
  TRANSPOSE16(B)
  unsigned act = 0xFFFFFFFFu, gt = 0u, Tv = 0u;
  int rem = 32;
#pragma unroll
  for (int bit = 15; bit >= 0; --bit) {
    unsigned bm = B[15 - bit] & act;
    int c = __popc(bm);
#pragma unroll
    for (int d = 1; d < 64; d <<= 1) c += __shfl_xor(c, d);
    bool take = (c >= rem);
    unsigned actx = act ^ bm;
    act = take ? bm : actx;
    gt = take ? gt : (gt | bm);
    rem = take ? rem : (rem - c);
    Tv = take ? (Tv | (1u << bit)) : Tv;
  }
  unsigned hT = (Tv & 0x8000u) ? (Tv ^ 0x8000u) : (Tv ^ 0xFFFFu);
  float vT = bf2f((unsigned short)hT);

  gt = pos2elem(gt);
  act = pos2elem(act);

  int pc_tie = __popc(act);
  int inc = pc_tie;
#pragma unroll
  for (int d = 1; d < 64; d <<= 1) { int y = __shfl_up(inc, d); if (lane >= d) inc += y; }
  int tie_pre = inc - pc_tie;
  int budget = rem - tie_pre;
  budget = budget < 0 ? 0 : (budget > pc_tie ? pc_tie : budget);
  int total_lane = __popc(gt) + budget;
  int inc2 = total_lane;
#pragma unroll
  for (int d = 1; d < 64; d <<= 1) { int y = __shfl_up(inc2, d); if (lane >= d) inc2 += y; }
  int slot = inc2 - total_lane;

  float lsum = 0.f;
  unsigned m = gt;
  while (m) {
    int e = __builtin_ctz(m); m &= m - 1;
    int gidx = (lane << 5) + e;
    float v = bf2f(rowp[gidx]);
    float ev = __expf((v - vT) * 0.125f);
    pS[w][slot] = ev; sS[w][slot] = gidx; ++slot; lsum += ev;
  }
  m = act;
  for (int taken = 0; taken < budget; ++taken) {
    int e = __builtin_ctz(m); m &= m - 1;
    int gidx = (lane << 5) + e;
    float v = bf2f(rowp[gidx]);
    float ev = __expf((v - vT) * 0.125f);
    pS[w][slot] = ev; sS[w][slot] = gidx; ++slot; lsum += ev;
  }
  float den = lsum;
#pragma unroll
  for (int d = 1; d < 64; d <<= 1) den += __shfl_xor(den, d);

  float acc = 0.f;
  const unsigned short* Vb = Pseqs + (size_t)(b * 2048) * NC + 1024 + h * 64 + lane;
#pragma unroll 8
  for (int t = 0; t < 32; ++t) {
    float pv = pS[w][t];
    int s = sS[w][t];
    acc += pv * bf2f(Vb[(size_t)s * NC]);
  }
  seqs_out[(size_t)(b * 128 + l) * 512 + h * 64 + lane] = acc / den;
}

// ---------------- pool 1b (softmax over fused logits + weighted sum) ----------------
// grid 256: b = bi>>4, ls = (bi>>1)&7, colhalf = bi&1
__global__ __launch_bounds__(256) void kpool1b(const unsigned short* __restrict__ x,
                                               const float* __restrict__ logits,
                                               float* __restrict__ aout, float* __restrict__ pp) {
  __shared__ float red[256];
  __shared__ float aS[256];
  int t = threadIdx.x;
  int b = blockIdx.x >> 4, ls = (blockIdx.x >> 1) & 7, cj = blockIdx.x & 1;
  const float* lg = logits + b * 2048;
  float lm = -FLT_MAX;
  for (int j = t; j < 2048; j += 256) lm = fmaxf(lm, lg[j]);
  red[t] = lm; __syncthreads();
  for (int s = 128; s > 0; s >>= 1) { if (t < s) red[t] = fmaxf(red[t], red[t + s]); __syncthreads(); }
  float M = red[0]; __syncthreads();
  float sm = 0.f;
  for (int j = t; j < 2048; j += 256) sm += __expf(lg[j] - M);
  red[t] = sm; __syncthreads();
  for (int s = 128; s > 0; s >>= 1) { if (t < s) red[t] += red[t + s]; __syncthreads(); }
  float D = red[0];
  int l0 = ls * 256;
  float a = __expf(lg[l0 + t] - M) / D;
  aS[t] = a;
  if (cj == 0) aout[b * 2048 + l0 + t] = a;
  __syncthreads();
  int col = cj * 256 + t;
  float acc0 = 0.f;
  const unsigned short* xb = x + ((size_t)b * 2048 + l0) * 512 + col;
#pragma unroll 8
  for (int ll = 0; ll < 256; ++ll) acc0 += aS[ll] * bf2f(xb[(size_t)ll * 512]);
  pp[(size_t)(b * 8 + ls) * 512 + col] = acc0;
}

// ---------------- pool 2 + emb (fused): per-b softmax pool over seqs_out, concat, l2-norm ----------------
__global__ __launch_bounds__(256) void kpool2emb(const float* __restrict__ x,
                                                 const float* __restrict__ wp, const float* __restrict__ bp,
                                                 const float* __restrict__ pp,
                                                 float* __restrict__ a2out, float* __restrict__ embo) {
  __shared__ float lgS[128];
  __shared__ float red[256];
  int t = threadIdx.x, lane = t & 63, wave = t >> 6;
  int b = blockIdx.x;
  for (int i = 0; i < 32; ++i) {
    int row = wave * 32 + i;
    const float* xp = x + (size_t)(b * 128 + row) * 512;
    float acc = 0.f;
#pragma unroll
    for (int j = 0; j < 8; ++j) acc += xp[lane + 64 * j] * wp[lane + 64 * j];
#pragma unroll
    for (int d = 1; d < 64; d <<= 1) acc += __shfl_xor(acc, d);
    if (lane == 0) lgS[row] = acc + bp[0];
  }
  __syncthreads();
  if (wave == 0) {
    float a0 = lgS[lane], a1 = lgS[64 + lane];
    float m = fmaxf(a0, a1);
#pragma unroll
    for (int d = 1; d < 64; d <<= 1) m = fmaxf(m, __shfl_xor(m, d));
    float e0 = __expf(a0 - m), e1 = __expf(a1 - m);
    float sden = e0 + e1;
#pragma unroll
    for (int d = 1; d < 64; d <<= 1) sden += __shfl_xor(sden, d);
    a0 = e0 / sden; a1 = e1 / sden;
    lgS[lane] = a0; lgS[64 + lane] = a1;
    a2out[b * 128 + lane] = a0;
    a2out[b * 128 + 64 + lane] = a1;
  }
  __syncthreads();
  float acc0 = 0.f, acc1 = 0.f;
#pragma unroll 4
  for (int row = 0; row < 128; ++row) {
    float av = lgS[row];
    const float* xp = x + (size_t)(b * 128 + row) * 512;
    acc0 += av * xp[t];
    acc1 += av * xp[t + 256];
  }
  // emb: cols t, 256+t from pp sums; 512+t = acc0; 768+t = acc1
  float pre0 = 0.f, pre1 = 0.f;
  for (int lsl = 0; lsl < 8; ++lsl) {
    pre0 += pp[(size_t)(b * 8 + lsl) * 512 + t];
    pre1 += pp[(size_t)(b * 8 + lsl) * 512 + 256 + t];
  }
  float ssq = pre0 * pre0 + pre1 * pre1 + acc0 * acc0 + acc1 * acc1;
  red[t] = ssq; __syncthreads();
  for (int s2 = 128; s2 > 0; s2 >>= 1) { if (t < s2) red[t] += red[t + s2]; __syncthreads(); }
  float inv = 1.f / fmaxf(sqrtf(red[0]), 1e-12f);
  embo[(size_t)b * 1024 + t] = pre0 * inv;
  embo[(size_t)b * 1024 + 256 + t] = pre1 * inv;
  embo[(size_t)b * 1024 + 512 + t] = acc0 * inv;
  embo[(size_t)b * 1024 + 768 + t] = acc1 * inv;
}

// ---------------- head ----------------
__global__ __launch_bounds__(256) void kmlp(const float* __restrict__ in, const float* __restrict__ W,
                                            const float* __restrict__ bias, float* __restrict__ out,
                                            int IN, int ON) {
  __shared__ float e[1024];
  int t = threadIdx.x;
  int chunks = ON >> 8;
  int b = blockIdx.x / chunks, jc = blockIdx.x % chunks;
  for (int q = t; q < IN; q += 256) e[q] = in[(size_t)b * IN + q];
  __syncthreads();
  int j = jc * 256 + t;
  float acc = bias[j];
#pragma unroll 8
  for (int i = 0; i < IN; ++i) acc += e[i] * W[(size_t)i * ON + j];
  out[(size_t)b * ON + j] = fmaxf(acc, 0.f);
}

// layer2 (1024->512, relu) + out head (512->1) fused; grid 16
__global__ __launch_bounds__(256) void kmlp2out(const float* __restrict__ h1, const float* __restrict__ W2,
                                                const float* __restrict__ b2, const float* __restrict__ W3,
                                                const float* __restrict__ b3, float* __restrict__ outp) {
  __shared__ float e[1024];
  __shared__ float red[256];
  int t = threadIdx.x, b = blockIdx.x;
  for (int q = t; q < 1024; q += 256) e[q] = h1[(size_t)b * 1024 + q];
  __syncthreads();
  int j0 = t, j1 = t + 256;
  float acc0 = b2[j0], acc1 = b2[j1];
#pragma unroll 8
  for (int i = 0; i < 1024; ++i) {
    float ei = e[i];
    acc0 += ei * W2[(size_t)i * 512 + j0];
    acc1 += ei * W2[(size_t)i * 512 + j1];
  }
  acc0 = fmaxf(acc0, 0.f); acc1 = fmaxf(acc1, 0.f);
  float s = acc0 * W3[j0] + acc1 * W3[j1];
  red[t] = s; __syncthreads();
  for (int st = 128; st > 0; st >>= 1) { if (t < st) red[t] += red[t + st]; __syncthreads(); }
  if (t == 0) outp[b] = red[0] + b3[0];
}

// ---------------- launch ----------------
extern "C" void kernel_launch(void* const* d_in, const int* in_sizes, int n_in,
                              void* d_out, int out_size, void* d_ws, size_t ws_size,
                              hipStream_t stream) {
  const float* seqs = (const float*)d_in[0];
  const float* smis = (const float*)d_in[1];
  const float* Wq = (const float*)d_in[2];
  const float* bq = (const float*)d_in[3];
  const float* Wk = (const float*)d_in[4];
  const float* bk = (const float*)d_in[5];
  const float* Wv = (const float*)d_in[6];
  const float* bv = (const float*)d_in[7];
  const float* wp = (const float*)d_in[8];
  const float* bp = (const float*)d_in[9];
  const float* W1 = (const float*)d_in[10];
  const float* b1 = (const float*)d_in[11];
  const float* W2 = (const float*)d_in[12];
  const float* b2 = (const float*)d_in[13];
  const float* W3 = (const float*)d_in[14];
  const float* b3 = (const float*)d_in[15];
  float* out = (float*)d_out;
  char* ws = (char*)d_ws;

  float* nrm_s = (float*)(ws + WS_NRM_S);
  float* nrm_m = (float*)(ws + WS_NRM_M);
  float* part_s = (float*)(ws + WS_PART);
  float* part_m = (float*)(ws + WS_PARTM);
  float* bcat = (float*)(ws + WS_BCAT);
  float* log1 = (float*)(ws + WS_LOG1);
  float* pp1 = (float*)(ws + WS_PP1);
  float* h1 = (float*)(ws + WS_H1);
  unsigned short* wct = (unsigned short*)(ws + WS_WCT);
  unsigned short* smis_nb = (unsigned short*)(ws + WS_SMISNB);
  unsigned short* Psmis = (unsigned short*)(ws + WS_PSMIS);
  float* seqs_out = (float*)(ws + WS_SEQSOUT);
  unsigned short* seqs_nb = (unsigned short*)(ws + WS_SEQSNB);
  unsigned short* Pseqs = (unsigned short*)(ws + WS_PSEQS);
  unsigned short* smil = (unsigned short*)(ws + WS_SMILOUT);
  unsigned short* S2 = (unsigned short*)(ws + WS_S2);

  // 1. column norms (part buffers alias Pseqs region; consumed before kgemm writes it)
  knorm_part<<<dim3(68, 16), 128, 0, stream>>>(seqs, smis, part_s, part_m);
  knorm_fin<<<dim3(64), 256, 0, stream>>>(part_s, part_m, nrm_s, nrm_m);
  // 2. normalize + cast to bf16 (both inputs)
  kcast<<<dim3(17408), 256, 0, stream>>>(seqs, smis, nrm_s, nrm_m, seqs_nb, smis_nb);
  // 3. weight prep (+ zero pool-1 logits)
  kprepw<<<dim3(16, 16, 3), 256, 0, stream>>>(Wq, Wk, Wv, wct);
  kprepbz<<<dim3(134), 256, 0, stream>>>(bq, bk, bv, bcat, log1);
  // 4. fused QKV projections (big + small in one dispatch)
  kgemm<<<dim3(3264), 256, 0, stream>>>(seqs_nb, smis_nb, wct, bcat, Pseqs, Psmis);
  // 5. fusion 1 attention + fused pool-1 logits
  kfusion1<<<dim3(32, 8, 16), 256, 0, stream>>>(Pseqs, Psmis, wp, smil, log1);
  // 6. pool 1 softmax + weighted sum
  kpool1b<<<dim3(256), 256, 0, stream>>>(smil, log1, out + OUT_A1, pp1);
  // 7. fusion 2
  kf2scores<<<dim3(16, 128), 256, 0, stream>>>(Psmis, Pseqs, S2);
  kf2select<<<dim3(4096), 256, 0, stream>>>(S2, Pseqs, seqs_out);
  kpool2emb<<<dim3(16), 256, 0, stream>>>(seqs_out, wp, bp, pp1, out + OUT_A2, out + OUT_EMB);
  // 8. head
  kmlp<<<dim3(64), 256, 0, stream>>>(out + OUT_EMB, W1, b1, h1, 1024, 1024);
  kmlp2out<<<dim3(16), 256, 0, stream>>>(h1, W2, b2, W3, b3, out + OUT_OUT);
}